// Round 2
// baseline (1627.285 us; speedup 1.0000x reference)
//
#include <hip/hip_runtime.h>
#include <hip/hip_bf16.h>

// GAT: N=50000 nodes, E=500000 edges, IN=256, HID=64, H=4 heads (H*HID=256)
#define NN 50000
#define NE 500000
#define C_IN 256
#define C_HID 64
#define C_H 4
#define C_HH 256  // H*HID

__device__ __forceinline__ float lrelu(float x) { return x > 0.f ? x : 0.2f * x; }

// ---------------- GEMM: C[M,NC] = A[M,K] @ W[K,NC] (+bias) ----------------
// Block = NC threads (one column each), RPB=32 rows staged in LDS.
template <int K, int NC, bool BIAS>
__global__ __launch_bounds__(NC) void gemm_kernel(const float* __restrict__ A,
                                                  const float* __restrict__ W,
                                                  const float* __restrict__ B,
                                                  float* __restrict__ C, int M) {
  constexpr int RPB = 32;
  __shared__ float As[RPB * K];
  const int row0 = blockIdx.x * RPB;
  const int tid = threadIdx.x;
  const int maxRows = min(RPB, M - row0);

  // cooperative load of the A tile (contiguous rows -> flat coalesced float4)
  const float4* Ag = reinterpret_cast<const float4*>(A + (size_t)row0 * K);
  float4* As4 = reinterpret_cast<float4*>(As);
  const int tot4 = maxRows * (K / 4);
  for (int i = tid; i < tot4; i += NC) As4[i] = Ag[i];
  __syncthreads();

  float acc[RPB];
#pragma unroll
  for (int r = 0; r < RPB; ++r) acc[r] = 0.f;

  const int j = tid;
  for (int k4 = 0; k4 < K; k4 += 4) {
    const float w0 = W[(k4 + 0) * NC + j];
    const float w1 = W[(k4 + 1) * NC + j];
    const float w2 = W[(k4 + 2) * NC + j];
    const float w3 = W[(k4 + 3) * NC + j];
#pragma unroll
    for (int r = 0; r < RPB; ++r) {
      float4 a = As4[r * (K / 4) + (k4 >> 2)];  // LDS broadcast (conflict-free)
      acc[r] = fmaf(a.x, w0, acc[r]);
      acc[r] = fmaf(a.y, w1, acc[r]);
      acc[r] = fmaf(a.z, w2, acc[r]);
      acc[r] = fmaf(a.w, w3, acc[r]);
    }
  }

  const float b = BIAS ? B[j] : 0.f;
  for (int r = 0; r < maxRows; ++r) {
    C[(size_t)(row0 + r) * NC + j] = acc[r] + b;
  }
}

// ---------------- el/er: el[n][h] = sum_f feat[n][h*64+f]*al[h*64+f] ----------------
__global__ __launch_bounds__(256) void attn_coef_kernel(const float* __restrict__ feat,
                                                        const float* __restrict__ al,
                                                        const float* __restrict__ ar,
                                                        float* __restrict__ el,
                                                        float* __restrict__ er) {
  const int node = blockIdx.x * 4 + (threadIdx.x >> 6);
  const int lane = threadIdx.x & 63;
  const float* f = feat + (size_t)node * C_HH;
#pragma unroll
  for (int h = 0; h < C_H; ++h) {
    const float v = f[h * 64 + lane];
    float sl = v * al[h * 64 + lane];
    float sr = v * ar[h * 64 + lane];
#pragma unroll
    for (int off = 32; off; off >>= 1) {
      sl += __shfl_xor(sl, off);
      sr += __shfl_xor(sr, off);
    }
    if (lane == 0) {
      el[node * C_H + h] = sl;
      er[node * C_H + h] = sr;
    }
  }
}

// ---------------- edge softmax denominator: s[dst][h] += exp(leaky(el[src]+er[dst])) ----------------
__global__ __launch_bounds__(256) void edge_sum_kernel(const int* __restrict__ src,
                                                       const int* __restrict__ dst,
                                                       const float* __restrict__ el,
                                                       const float* __restrict__ er,
                                                       float* __restrict__ s) {
  const int e = blockIdx.x * blockDim.x + threadIdx.x;
  if (e >= NE) return;
  const int sn = src[e], dn = dst[e];
  const float4 a = *reinterpret_cast<const float4*>(el + sn * 4);
  const float4 b = *reinterpret_cast<const float4*>(er + dn * 4);
  atomicAdd(&s[dn * 4 + 0], __expf(lrelu(a.x + b.x)));
  atomicAdd(&s[dn * 4 + 1], __expf(lrelu(a.y + b.y)));
  atomicAdd(&s[dn * 4 + 2], __expf(lrelu(a.z + b.z)));
  atomicAdd(&s[dn * 4 + 3], __expf(lrelu(a.w + b.w)));
}

// ---------------- aggregation: out[dst] += alpha * feat[src] (one 64-lane wave per edge) ----------------
__global__ __launch_bounds__(256) void edge_aggr_kernel(const int* __restrict__ src,
                                                        const int* __restrict__ dst,
                                                        const float* __restrict__ el,
                                                        const float* __restrict__ er,
                                                        const float* __restrict__ s,
                                                        const float* __restrict__ feat,
                                                        float* __restrict__ out) {
  const int e = blockIdx.x * 4 + (threadIdx.x >> 6);
  const int lane = threadIdx.x & 63;
  if (e >= NE) return;
  const int sn = src[e], dn = dst[e];
  const float4 a = *reinterpret_cast<const float4*>(el + sn * 4);
  const float4 b = *reinterpret_cast<const float4*>(er + dn * 4);
  const float4 sd = *reinterpret_cast<const float4*>(s + dn * 4);
  const float al0 = __expf(lrelu(a.x + b.x)) / sd.x;
  const float al1 = __expf(lrelu(a.y + b.y)) / sd.y;
  const float al2 = __expf(lrelu(a.z + b.z)) / sd.z;
  const float al3 = __expf(lrelu(a.w + b.w)) / sd.w;
  const float* fs = feat + (size_t)sn * C_HH;
  float* od = out + (size_t)dn * C_HH;
  atomicAdd(&od[0 * 64 + lane], al0 * fs[0 * 64 + lane]);
  atomicAdd(&od[1 * 64 + lane], al1 * fs[1 * 64 + lane]);
  atomicAdd(&od[2 * 64 + lane], al2 * fs[2 * 64 + lane]);
  atomicAdd(&od[3 * 64 + lane], al3 * fs[3 * 64 + lane]);
}

// ---------------- bias + relu, in place over [N, 256] ----------------
__global__ __launch_bounds__(256) void bias_relu_kernel(float* __restrict__ h,
                                                        const float* __restrict__ b) {
  const int i = blockIdx.x * blockDim.x + threadIdx.x;  // over N*256/4 float4s
  float4 v = reinterpret_cast<float4*>(h)[i];
  const float4 bb = reinterpret_cast<const float4*>(b)[i & 63];
  v.x = fmaxf(v.x + bb.x, 0.f);
  v.y = fmaxf(v.y + bb.y, 0.f);
  v.z = fmaxf(v.z + bb.z, 0.f);
  v.w = fmaxf(v.w + bb.w, 0.f);
  reinterpret_cast<float4*>(h)[i] = v;
}

// ---------------- final projection p2 + sigmoid ----------------
__global__ __launch_bounds__(256) void proj2_kernel(const float* __restrict__ t1,
                                                    const float* __restrict__ p2w,
                                                    const float* __restrict__ p2b,
                                                    float* __restrict__ out) {
  const int node = blockIdx.x * 4 + (threadIdx.x >> 6);
  const int lane = threadIdx.x & 63;
  float v = t1[node * 64 + lane] * p2w[lane];
#pragma unroll
  for (int off = 32; off; off >>= 1) v += __shfl_xor(v, off);
  if (lane == 0) out[node] = 1.f / (1.f + __expf(-(v + p2b[0])));
}

extern "C" void kernel_launch(void* const* d_in, const int* in_sizes, int n_in,
                              void* d_out, int out_size, void* d_ws, size_t ws_size,
                              hipStream_t stream) {
  const float* x = (const float*)d_in[0];
  const int* src = (const int*)d_in[1];
  const int* dst = (const int*)d_in[2];
  const float* embed_W = (const float*)d_in[3];
  const float* embed_b = (const float*)d_in[4];
  const float* W1 = (const float*)d_in[5];
  const float* al1 = (const float*)d_in[6];
  const float* ar1 = (const float*)d_in[7];
  const float* b1 = (const float*)d_in[8];
  const float* W2 = (const float*)d_in[9];
  const float* al2 = (const float*)d_in[10];
  const float* ar2 = (const float*)d_in[11];
  const float* b2 = (const float*)d_in[12];
  const float* p1_W = (const float*)d_in[13];
  const float* p1_b = (const float*)d_in[14];
  const float* p2_W = (const float*)d_in[15];
  const float* p2_b = (const float*)d_in[16];

  char* ws = (char*)d_ws;
  float* h0 = (float*)(ws + 0);            // N*64  = 12.8 MB
  float* feat = (float*)(ws + 12800000);   // N*256 = 51.2 MB
  float* hout = (float*)(ws + 64000000);   // N*256 = 51.2 MB
  float* el = (float*)(ws + 115200000);    // N*4
  float* er = (float*)(ws + 116000000);    // N*4
  float* s = (float*)(ws + 116800000);     // N*4
  float* t1 = (float*)(ws + 117600000);    // N*64 = 12.8 MB

  const int gRows = (NN + 31) / 32;  // 1563

  // embed: h0 = x @ embed_W + embed_b
  gemm_kernel<256, 64, true><<<gRows, 64, 0, stream>>>(x, embed_W, embed_b, h0, NN);

  // ---- GAT layer 1 ----
  gemm_kernel<64, 256, false><<<gRows, 256, 0, stream>>>(h0, W1, nullptr, feat, NN);
  attn_coef_kernel<<<NN / 4, 256, 0, stream>>>(feat, al1, ar1, el, er);
  hipMemsetAsync(s, 0, NN * 4 * sizeof(float), stream);
  edge_sum_kernel<<<(NE + 255) / 256, 256, 0, stream>>>(src, dst, el, er, s);
  hipMemsetAsync(hout, 0, (size_t)NN * 256 * sizeof(float), stream);
  edge_aggr_kernel<<<NE / 4, 256, 0, stream>>>(src, dst, el, er, s, feat, hout);
  bias_relu_kernel<<<(NN * 256 / 4) / 256, 256, 0, stream>>>(hout, b1);

  // ---- GAT layer 2 ----
  gemm_kernel<256, 256, false><<<gRows, 256, 0, stream>>>(hout, W2, nullptr, feat, NN);
  attn_coef_kernel<<<NN / 4, 256, 0, stream>>>(feat, al2, ar2, el, er);
  hipMemsetAsync(s, 0, NN * 4 * sizeof(float), stream);
  edge_sum_kernel<<<(NE + 255) / 256, 256, 0, stream>>>(src, dst, el, er, s);
  hipMemsetAsync(hout, 0, (size_t)NN * 256 * sizeof(float), stream);
  edge_aggr_kernel<<<NE / 4, 256, 0, stream>>>(src, dst, el, er, s, feat, hout);
  bias_relu_kernel<<<(NN * 256 / 4) / 256, 256, 0, stream>>>(hout, b2);

  // ---- head: t1 = hout @ p1_W + p1_b ; out = sigmoid(t1 @ p2_W + p2_b) ----
  gemm_kernel<256, 64, true><<<gRows, 64, 0, stream>>>(hout, p1_W, p1_b, t1, NN);
  proj2_kernel<<<NN / 4, 256, 0, stream>>>(t1, p2_W, p2_b, (float*)d_out);
}

// Round 3
// 787.796 us; speedup vs baseline: 2.0656x; 2.0656x over previous
//
#include <hip/hip_runtime.h>
#include <hip/hip_bf16.h>

// GAT: N=50000 nodes, E=500000 edges, IN=256, HID=64, H=4 heads (H*HID=256)
#define NN 50000
#define NE 500000
#define C_HH 256  // H*HID

__device__ __forceinline__ float lrelu(float x) { return x > 0.f ? x : 0.2f * x; }

// ---------------- GEMM: C[M,NC] = A[M,K] @ W[K,NC] (+bias) ----------------
template <int K, int NC, bool BIAS>
__global__ __launch_bounds__(NC) void gemm_kernel(const float* __restrict__ A,
                                                  const float* __restrict__ W,
                                                  const float* __restrict__ B,
                                                  float* __restrict__ C, int M) {
  constexpr int RPB = 32;
  __shared__ float As[RPB * K];
  const int row0 = blockIdx.x * RPB;
  const int tid = threadIdx.x;
  const int maxRows = min(RPB, M - row0);

  const float4* Ag = reinterpret_cast<const float4*>(A + (size_t)row0 * K);
  float4* As4 = reinterpret_cast<float4*>(As);
  const int tot4 = maxRows * (K / 4);
  for (int i = tid; i < tot4; i += NC) As4[i] = Ag[i];
  __syncthreads();

  float acc[RPB];
#pragma unroll
  for (int r = 0; r < RPB; ++r) acc[r] = 0.f;

  const int j = tid;
  for (int k4 = 0; k4 < K; k4 += 4) {
    const float w0 = W[(k4 + 0) * NC + j];
    const float w1 = W[(k4 + 1) * NC + j];
    const float w2 = W[(k4 + 2) * NC + j];
    const float w3 = W[(k4 + 3) * NC + j];
#pragma unroll
    for (int r = 0; r < RPB; ++r) {
      float4 a = As4[r * (K / 4) + (k4 >> 2)];
      acc[r] = fmaf(a.x, w0, acc[r]);
      acc[r] = fmaf(a.y, w1, acc[r]);
      acc[r] = fmaf(a.z, w2, acc[r]);
      acc[r] = fmaf(a.w, w3, acc[r]);
    }
  }

  const float b = BIAS ? B[j] : 0.f;
  for (int r = 0; r < maxRows; ++r) {
    C[(size_t)(row0 + r) * NC + j] = acc[r] + b;
  }
}

// ---------------- el/er per node ----------------
__global__ __launch_bounds__(256) void attn_coef_kernel(const float* __restrict__ feat,
                                                        const float* __restrict__ al,
                                                        const float* __restrict__ ar,
                                                        float* __restrict__ el,
                                                        float* __restrict__ er) {
  const int node = blockIdx.x * 4 + (threadIdx.x >> 6);
  const int lane = threadIdx.x & 63;
  const float* f = feat + (size_t)node * C_HH;
#pragma unroll
  for (int h = 0; h < 4; ++h) {
    const float v = f[h * 64 + lane];
    float sl = v * al[h * 64 + lane];
    float sr = v * ar[h * 64 + lane];
#pragma unroll
    for (int off = 32; off; off >>= 1) {
      sl += __shfl_xor(sl, off);
      sr += __shfl_xor(sr, off);
    }
    if (lane == 0) {
      el[node * 4 + h] = sl;
      er[node * 4 + h] = sr;
    }
  }
}

// ---------------- CSR build: histogram -> scan -> scatter ----------------
__global__ __launch_bounds__(256) void hist_kernel(const int* __restrict__ dst,
                                                   int* __restrict__ rowptr) {
  const int e = blockIdx.x * 256 + threadIdx.x;
  if (e < NE) atomicAdd(&rowptr[dst[e]], 1);
}

// block-level exclusive scan of 256 deg values; partial[b] = block total
__global__ __launch_bounds__(256) void scan1_kernel(int* __restrict__ rowptr,
                                                    int* __restrict__ partial) {
  __shared__ int sh[256];
  const int t = threadIdx.x;
  const int i = blockIdx.x * 256 + t;
  const int v = (i < NN) ? rowptr[i] : 0;
  sh[t] = v;
  __syncthreads();
#pragma unroll
  for (int off = 1; off < 256; off <<= 1) {
    int x = (t >= off) ? sh[t - off] : 0;
    __syncthreads();
    sh[t] += x;
    __syncthreads();
  }
  if (i < NN) rowptr[i] = sh[t] - v;  // exclusive within block
  if (t == 255) partial[blockIdx.x] = sh[255];
}

// exclusive scan of the block partials (<=256 of them), in place
__global__ __launch_bounds__(256) void scan2_kernel(int* __restrict__ partial, int npb) {
  __shared__ int sh[256];
  const int t = threadIdx.x;
  const int v = (t < npb) ? partial[t] : 0;
  sh[t] = v;
  __syncthreads();
#pragma unroll
  for (int off = 1; off < 256; off <<= 1) {
    int x = (t >= off) ? sh[t - off] : 0;
    __syncthreads();
    sh[t] += x;
    __syncthreads();
  }
  if (t < npb) partial[t] = sh[t] - v;
}

// add block offsets; produce final rowptr and cursor copy
__global__ __launch_bounds__(256) void scan3_kernel(int* __restrict__ rowptr,
                                                    const int* __restrict__ partial,
                                                    int* __restrict__ cursor) {
  const int i = blockIdx.x * 256 + threadIdx.x;
  if (i < NN) {
    const int r = rowptr[i] + partial[i >> 8];
    rowptr[i] = r;
    cursor[i] = r;
  } else if (i == NN) {
    rowptr[NN] = NE;
  }
}

__global__ __launch_bounds__(256) void scatter_kernel(const int* __restrict__ src,
                                                      const int* __restrict__ dst,
                                                      int* __restrict__ cursor,
                                                      int* __restrict__ sorted_src) {
  const int e = blockIdx.x * 256 + threadIdx.x;
  if (e >= NE) return;
  const int pos = atomicAdd(&cursor[dst[e]], 1);
  sorted_src[pos] = src[e];
}

// ---------------- fused per-dst softmax-aggregation + bias + relu ----------------
// one 64-lane wave per dst node; 4 accumulators/lane (one per head)
__global__ __launch_bounds__(256) void aggr_fused_kernel(const int* __restrict__ rowptr,
                                                         const int* __restrict__ sorted_src,
                                                         const float* __restrict__ el,
                                                         const float* __restrict__ er,
                                                         const float* __restrict__ feat,
                                                         const float* __restrict__ bias,
                                                         float* __restrict__ out) {
  const int node = blockIdx.x * 4 + (threadIdx.x >> 6);
  const int lane = threadIdx.x & 63;
  const int start = rowptr[node];
  const int end = rowptr[node + 1];
  const float4 erd = *reinterpret_cast<const float4*>(er + node * 4);

  float a0 = 0.f, a1 = 0.f, a2 = 0.f, a3 = 0.f;
  float s0 = 0.f, s1 = 0.f, s2 = 0.f, s3 = 0.f;
  for (int e = start; e < end; ++e) {
    const int sn = sorted_src[e];
    const float4 a = *reinterpret_cast<const float4*>(el + sn * 4);
    const float w0 = __expf(lrelu(a.x + erd.x));
    const float w1 = __expf(lrelu(a.y + erd.y));
    const float w2 = __expf(lrelu(a.z + erd.z));
    const float w3 = __expf(lrelu(a.w + erd.w));
    const float* fs = feat + (size_t)sn * C_HH;
    a0 = fmaf(w0, fs[0 * 64 + lane], a0);
    a1 = fmaf(w1, fs[1 * 64 + lane], a1);
    a2 = fmaf(w2, fs[2 * 64 + lane], a2);
    a3 = fmaf(w3, fs[3 * 64 + lane], a3);
    s0 += w0; s1 += w1; s2 += w2; s3 += w3;
  }
  float r0 = 0.f, r1 = 0.f, r2 = 0.f, r3 = 0.f;
  if (end > start) {
    r0 = a0 / s0; r1 = a1 / s1; r2 = a2 / s2; r3 = a3 / s3;
  }
  float* od = out + (size_t)node * C_HH;
  od[0 * 64 + lane] = fmaxf(r0 + bias[0 * 64 + lane], 0.f);
  od[1 * 64 + lane] = fmaxf(r1 + bias[1 * 64 + lane], 0.f);
  od[2 * 64 + lane] = fmaxf(r2 + bias[2 * 64 + lane], 0.f);
  od[3 * 64 + lane] = fmaxf(r3 + bias[3 * 64 + lane], 0.f);
}

// ---------------- final projection p2 + sigmoid ----------------
__global__ __launch_bounds__(256) void proj2_kernel(const float* __restrict__ t1,
                                                    const float* __restrict__ p2w,
                                                    const float* __restrict__ p2b,
                                                    float* __restrict__ out) {
  const int node = blockIdx.x * 4 + (threadIdx.x >> 6);
  const int lane = threadIdx.x & 63;
  float v = t1[node * 64 + lane] * p2w[lane];
#pragma unroll
  for (int off = 32; off; off >>= 1) v += __shfl_xor(v, off);
  if (lane == 0) out[node] = 1.f / (1.f + __expf(-(v + p2b[0])));
}

extern "C" void kernel_launch(void* const* d_in, const int* in_sizes, int n_in,
                              void* d_out, int out_size, void* d_ws, size_t ws_size,
                              hipStream_t stream) {
  const float* x = (const float*)d_in[0];
  const int* src = (const int*)d_in[1];
  const int* dst = (const int*)d_in[2];
  const float* embed_W = (const float*)d_in[3];
  const float* embed_b = (const float*)d_in[4];
  const float* W1 = (const float*)d_in[5];
  const float* al1 = (const float*)d_in[6];
  const float* ar1 = (const float*)d_in[7];
  const float* b1 = (const float*)d_in[8];
  const float* W2 = (const float*)d_in[9];
  const float* al2 = (const float*)d_in[10];
  const float* ar2 = (const float*)d_in[11];
  const float* b2 = (const float*)d_in[12];
  const float* p1_W = (const float*)d_in[13];
  const float* p1_b = (const float*)d_in[14];
  const float* p2_W = (const float*)d_in[15];
  const float* p2_b = (const float*)d_in[16];

  char* ws = (char*)d_ws;
  float* h0 = (float*)(ws + 0);             // N*64 = 12.8 MB (aliased as t1 later)
  float* feat = (float*)(ws + 12800000);    // N*256 = 51.2 MB
  float* hout = (float*)(ws + 64000000);    // N*256 = 51.2 MB
  float* el = (float*)(ws + 115200000);     // N*4
  float* er = (float*)(ws + 116000000);     // N*4
  int* rowptr = (int*)(ws + 116800000);     // N+1 ints
  int* cursor = (int*)(ws + 117100000);     // N ints
  int* partial = (int*)(ws + 117400000);    // 256 ints
  int* sorted_src = (int*)(ws + 117500000); // E ints = 2 MB
  float* t1 = h0;                           // reuse: h0 dead after W1 GEMM

  const int gRows = (NN + 31) / 32;       // 1563
  const int gEdge = (NE + 255) / 256;     // 1954
  const int nScanB = (NN + 255) / 256;    // 196

  // ---- CSR build (dst shared by both layers) ----
  hipMemsetAsync(rowptr, 0, (NN + 1) * sizeof(int), stream);
  hist_kernel<<<gEdge, 256, 0, stream>>>(dst, rowptr);
  scan1_kernel<<<nScanB, 256, 0, stream>>>(rowptr, partial);
  scan2_kernel<<<1, 256, 0, stream>>>(partial, nScanB);
  scan3_kernel<<<nScanB + 1, 256, 0, stream>>>(rowptr, partial, cursor);
  scatter_kernel<<<gEdge, 256, 0, stream>>>(src, dst, cursor, sorted_src);

  // embed: h0 = x @ embed_W + embed_b
  gemm_kernel<256, 64, true><<<gRows, 64, 0, stream>>>(x, embed_W, embed_b, h0, NN);

  // ---- GAT layer 1 ----
  gemm_kernel<64, 256, false><<<gRows, 256, 0, stream>>>(h0, W1, nullptr, feat, NN);
  attn_coef_kernel<<<NN / 4, 256, 0, stream>>>(feat, al1, ar1, el, er);
  aggr_fused_kernel<<<NN / 4, 256, 0, stream>>>(rowptr, sorted_src, el, er, feat, b1, hout);

  // ---- GAT layer 2 ----
  gemm_kernel<256, 256, false><<<gRows, 256, 0, stream>>>(hout, W2, nullptr, feat, NN);
  attn_coef_kernel<<<NN / 4, 256, 0, stream>>>(feat, al2, ar2, el, er);
  aggr_fused_kernel<<<NN / 4, 256, 0, stream>>>(rowptr, sorted_src, el, er, feat, b2, hout);

  // ---- head ----
  gemm_kernel<256, 64, true><<<gRows, 64, 0, stream>>>(hout, p1_W, p1_b, t1, NN);
  proj2_kernel<<<NN / 4, 256, 0, stream>>>(t1, p2_W, p2_b, (float*)d_out);
}

// Round 4
// 532.130 us; speedup vs baseline: 3.0581x; 1.4805x over previous
//
#include <hip/hip_runtime.h>
#include <hip/hip_bf16.h>

// GAT: N=50000 nodes, E=500000 edges, IN=256, HID=64, H=4 heads (H*HID=256)
#define NN 50000
#define NE 500000
#define C_HH 256  // H*HID

typedef __attribute__((ext_vector_type(8))) short s16x8;
typedef __attribute__((ext_vector_type(4))) float f32x4;
typedef unsigned short ushort_t;

__device__ __forceinline__ float lrelu(float x) { return x > 0.f ? x : 0.2f * x; }

// fp32 -> bf16 (round to nearest even), as raw ushort bits
__device__ __forceinline__ ushort_t f2bf(float f) {
  unsigned u = __float_as_uint(f);
  u = (u + 0x7FFFu + ((u >> 16) & 1u)) >> 16;
  return (ushort_t)u;
}

// ---------------- fp32 -> bf16 bulk convert (8 elems/thread) ----------------
__global__ __launch_bounds__(256) void f2b_kernel(const float* __restrict__ in,
                                                  ushort_t* __restrict__ out, int n8) {
  const int i = blockIdx.x * 256 + threadIdx.x;
  if (i >= n8) return;
  const f32x4 v0 = reinterpret_cast<const f32x4*>(in)[2 * i];
  const f32x4 v1 = reinterpret_cast<const f32x4*>(in)[2 * i + 1];
  s16x8 o;
  o[0] = (short)f2bf(v0[0]); o[1] = (short)f2bf(v0[1]);
  o[2] = (short)f2bf(v0[2]); o[3] = (short)f2bf(v0[3]);
  o[4] = (short)f2bf(v1[0]); o[5] = (short)f2bf(v1[1]);
  o[6] = (short)f2bf(v1[2]); o[7] = (short)f2bf(v1[3]);
  reinterpret_cast<s16x8*>(out)[i] = o;
}

// ---------------- weight transpose-convert: W[K][NC] -> WT[NC][K] bf16 ----------------
__global__ __launch_bounds__(256) void wt_prep_kernel(const float* __restrict__ W,
                                                      ushort_t* __restrict__ WT,
                                                      int K, int NCOLS) {
  const int idx = blockIdx.x * 256 + threadIdx.x;
  if (idx >= K * NCOLS) return;
  const int n = idx / K, k = idx - n * K;
  WT[idx] = f2bf(W[k * NCOLS + n]);
}

// ---------------- MFMA GEMM: C[M,NC] = A[M,K](bf16) @ W[K,NC] (+bias) ----------------
// WT is [NC][K] bf16. Block: 256 thr = 4 waves, BM=128; wave w owns rows [32w,32w+32).
// mfma_f32_16x16x32_bf16; C/D layout: col=lane&15, row=(lane>>4)*4+reg (HW-verified).
template <int K, int NC, bool BIAS, bool OUT_BF16>
__global__ __launch_bounds__(256) void gemm_mfma(const ushort_t* __restrict__ A,
                                                 const ushort_t* __restrict__ WT,
                                                 const float* __restrict__ Bias,
                                                 void* __restrict__ Cout, int M) {
  constexpr int NT = NC / 16;  // n-tiles
  constexpr int KS = K / 32;   // k-steps
  const int wid = threadIdx.x >> 6;
  const int lane = threadIdx.x & 63;
  const int row0 = blockIdx.x * 128 + wid * 32;
  const int rA = lane & 15;   // m-index (A) / n-index (B) / col (C)
  const int kg = lane >> 4;   // k-group 0..3

  f32x4 acc[2][NT] = {};
  const s16x8 zf = {0, 0, 0, 0, 0, 0, 0, 0};

  const bool v0 = (row0 + rA) < M;
  const bool v1 = (row0 + 16 + rA) < M;
  const ushort_t* Arow0 = A + (size_t)(row0 + rA) * K;
  const ushort_t* Arow1 = A + (size_t)(row0 + 16 + rA) * K;
  const ushort_t* Wrow = WT + rA * K;

  for (int ks = 0; ks < KS; ++ks) {
    const int k0 = ks * 32 + kg * 8;
    const s16x8 a0 = v0 ? *reinterpret_cast<const s16x8*>(Arow0 + k0) : zf;
    const s16x8 a1 = v1 ? *reinterpret_cast<const s16x8*>(Arow1 + k0) : zf;
#pragma unroll
    for (int nt = 0; nt < NT; ++nt) {
      const s16x8 b = *reinterpret_cast<const s16x8*>(Wrow + nt * 16 * K + k0);
      acc[0][nt] = __builtin_amdgcn_mfma_f32_16x16x32_bf16(a0, b, acc[0][nt], 0, 0, 0);
      acc[1][nt] = __builtin_amdgcn_mfma_f32_16x16x32_bf16(a1, b, acc[1][nt], 0, 0, 0);
    }
  }

#pragma unroll
  for (int nt = 0; nt < NT; ++nt) {
    const int col = nt * 16 + rA;
    const float bv = BIAS ? Bias[col] : 0.f;
#pragma unroll
    for (int mt = 0; mt < 2; ++mt) {
#pragma unroll
      for (int i = 0; i < 4; ++i) {
        const int row = row0 + mt * 16 + kg * 4 + i;
        if (row < M) {
          const float v = acc[mt][nt][i] + bv;
          if (OUT_BF16)
            reinterpret_cast<ushort_t*>(Cout)[(size_t)row * NC + col] = f2bf(v);
          else
            reinterpret_cast<float*>(Cout)[(size_t)row * NC + col] = v;
        }
      }
    }
  }
}

// ---------------- el/er per node (feat fp32) ----------------
__global__ __launch_bounds__(256) void attn_coef_kernel(const float* __restrict__ feat,
                                                        const float* __restrict__ al,
                                                        const float* __restrict__ ar,
                                                        float* __restrict__ el,
                                                        float* __restrict__ er) {
  const int node = blockIdx.x * 4 + (threadIdx.x >> 6);
  const int lane = threadIdx.x & 63;
  const float* f = feat + (size_t)node * C_HH;
#pragma unroll
  for (int h = 0; h < 4; ++h) {
    const float v = f[h * 64 + lane];
    float sl = v * al[h * 64 + lane];
    float sr = v * ar[h * 64 + lane];
#pragma unroll
    for (int off = 32; off; off >>= 1) {
      sl += __shfl_xor(sl, off);
      sr += __shfl_xor(sr, off);
    }
    if (lane == 0) {
      el[node * 4 + h] = sl;
      er[node * 4 + h] = sr;
    }
  }
}

// ---------------- CSR build: histogram -> scan -> scatter ----------------
__global__ __launch_bounds__(256) void hist_kernel(const int* __restrict__ dst,
                                                   int* __restrict__ rowptr) {
  const int e = blockIdx.x * 256 + threadIdx.x;
  if (e < NE) atomicAdd(&rowptr[dst[e]], 1);
}

__global__ __launch_bounds__(256) void scan1_kernel(int* __restrict__ rowptr,
                                                    int* __restrict__ partial) {
  __shared__ int sh[256];
  const int t = threadIdx.x;
  const int i = blockIdx.x * 256 + t;
  const int v = (i < NN) ? rowptr[i] : 0;
  sh[t] = v;
  __syncthreads();
#pragma unroll
  for (int off = 1; off < 256; off <<= 1) {
    int x = (t >= off) ? sh[t - off] : 0;
    __syncthreads();
    sh[t] += x;
    __syncthreads();
  }
  if (i < NN) rowptr[i] = sh[t] - v;
  if (t == 255) partial[blockIdx.x] = sh[255];
}

__global__ __launch_bounds__(256) void scan2_kernel(int* __restrict__ partial, int npb) {
  __shared__ int sh[256];
  const int t = threadIdx.x;
  const int v = (t < npb) ? partial[t] : 0;
  sh[t] = v;
  __syncthreads();
#pragma unroll
  for (int off = 1; off < 256; off <<= 1) {
    int x = (t >= off) ? sh[t - off] : 0;
    __syncthreads();
    sh[t] += x;
    __syncthreads();
  }
  if (t < npb) partial[t] = sh[t] - v;
}

__global__ __launch_bounds__(256) void scan3_kernel(int* __restrict__ rowptr,
                                                    const int* __restrict__ partial,
                                                    int* __restrict__ cursor) {
  const int i = blockIdx.x * 256 + threadIdx.x;
  if (i < NN) {
    const int r = rowptr[i] + partial[i >> 8];
    rowptr[i] = r;
    cursor[i] = r;
  } else if (i == NN) {
    rowptr[NN] = NE;
  }
}

__global__ __launch_bounds__(256) void scatter_kernel(const int* __restrict__ src,
                                                      const int* __restrict__ dst,
                                                      int* __restrict__ cursor,
                                                      int* __restrict__ sorted_src) {
  const int e = blockIdx.x * 256 + threadIdx.x;
  if (e >= NE) return;
  const int pos = atomicAdd(&cursor[dst[e]], 1);
  sorted_src[pos] = src[e];
}

// ---------------- fused per-dst softmax-aggregation + bias + relu -> bf16 ----------------
__global__ __launch_bounds__(256) void aggr_fused_kernel(const int* __restrict__ rowptr,
                                                         const int* __restrict__ sorted_src,
                                                         const float* __restrict__ el,
                                                         const float* __restrict__ er,
                                                         const float* __restrict__ feat,
                                                         const float* __restrict__ bias,
                                                         ushort_t* __restrict__ out) {
  const int node = blockIdx.x * 4 + (threadIdx.x >> 6);
  const int lane = threadIdx.x & 63;
  const int start = rowptr[node];
  const int end = rowptr[node + 1];
  const float4 erd = *reinterpret_cast<const float4*>(er + node * 4);

  float a0 = 0.f, a1 = 0.f, a2 = 0.f, a3 = 0.f;
  float s0 = 0.f, s1 = 0.f, s2 = 0.f, s3 = 0.f;
  for (int e = start; e < end; ++e) {
    const int sn = sorted_src[e];
    const float4 a = *reinterpret_cast<const float4*>(el + sn * 4);
    const float w0 = __expf(lrelu(a.x + erd.x));
    const float w1 = __expf(lrelu(a.y + erd.y));
    const float w2 = __expf(lrelu(a.z + erd.z));
    const float w3 = __expf(lrelu(a.w + erd.w));
    const float* fs = feat + (size_t)sn * C_HH;
    a0 = fmaf(w0, fs[0 * 64 + lane], a0);
    a1 = fmaf(w1, fs[1 * 64 + lane], a1);
    a2 = fmaf(w2, fs[2 * 64 + lane], a2);
    a3 = fmaf(w3, fs[3 * 64 + lane], a3);
    s0 += w0; s1 += w1; s2 += w2; s3 += w3;
  }
  float r0 = 0.f, r1 = 0.f, r2 = 0.f, r3 = 0.f;
  if (end > start) {
    r0 = a0 / s0; r1 = a1 / s1; r2 = a2 / s2; r3 = a3 / s3;
  }
  ushort_t* od = out + (size_t)node * C_HH;
  od[0 * 64 + lane] = f2bf(fmaxf(r0 + bias[0 * 64 + lane], 0.f));
  od[1 * 64 + lane] = f2bf(fmaxf(r1 + bias[1 * 64 + lane], 0.f));
  od[2 * 64 + lane] = f2bf(fmaxf(r2 + bias[2 * 64 + lane], 0.f));
  od[3 * 64 + lane] = f2bf(fmaxf(r3 + bias[3 * 64 + lane], 0.f));
}

// ---------------- final projection p2 + sigmoid ----------------
__global__ __launch_bounds__(256) void proj2_kernel(const float* __restrict__ t1,
                                                    const float* __restrict__ p2w,
                                                    const float* __restrict__ p2b,
                                                    float* __restrict__ out) {
  const int node = blockIdx.x * 4 + (threadIdx.x >> 6);
  const int lane = threadIdx.x & 63;
  float v = t1[node * 64 + lane] * p2w[lane];
#pragma unroll
  for (int off = 32; off; off >>= 1) v += __shfl_xor(v, off);
  if (lane == 0) out[node] = 1.f / (1.f + __expf(-(v + p2b[0])));
}

extern "C" void kernel_launch(void* const* d_in, const int* in_sizes, int n_in,
                              void* d_out, int out_size, void* d_ws, size_t ws_size,
                              hipStream_t stream) {
  const float* x = (const float*)d_in[0];
  const int* src = (const int*)d_in[1];
  const int* dst = (const int*)d_in[2];
  const float* embed_W = (const float*)d_in[3];
  const float* embed_b = (const float*)d_in[4];
  const float* W1 = (const float*)d_in[5];
  const float* al1 = (const float*)d_in[6];
  const float* ar1 = (const float*)d_in[7];
  const float* b1 = (const float*)d_in[8];
  const float* W2 = (const float*)d_in[9];
  const float* al2 = (const float*)d_in[10];
  const float* ar2 = (const float*)d_in[11];
  const float* b2 = (const float*)d_in[12];
  const float* p1_W = (const float*)d_in[13];
  const float* p1_b = (const float*)d_in[14];
  const float* p2_W = (const float*)d_in[15];
  const float* p2_b = (const float*)d_in[16];

  char* ws = (char*)d_ws;
  float* feat = (float*)(ws + 0);                 // N*256 f32 = 51.2 MB
  ushort_t* houtb = (ushort_t*)(ws + 51200000);   // N*256 bf16 = 25.6 MB
  ushort_t* xb = (ushort_t*)(ws + 76800000);      // N*256 bf16 = 25.6 MB (dead after embed)
  float* t1 = (float*)(ws + 76800000);            // N*64 f32 = 12.8 MB (aliases xb)
  ushort_t* h0b = (ushort_t*)(ws + 102400000);    // N*64 bf16 = 6.4 MB
  float* el = (float*)(ws + 108800000);           // N*4 f32
  float* er = (float*)(ws + 109600000);           // N*4 f32
  int* rowptr = (int*)(ws + 110400000);           // N+1
  int* cursor = (int*)(ws + 110700000);           // N
  int* partial = (int*)(ws + 111000000);          // 256
  int* sorted_src = (int*)(ws + 111100000);       // E = 2 MB
  ushort_t* eWT = (ushort_t*)(ws + 113200000);    // 64*256
  ushort_t* w1T = (ushort_t*)(ws + 113300000);    // 256*64
  ushort_t* w2T = (ushort_t*)(ws + 113400000);    // 256*256 = 128 KB
  ushort_t* p1T = (ushort_t*)(ws + 113600000);    // 64*256

  const int gEdge = (NE + 255) / 256;   // 1954
  const int nScanB = (NN + 255) / 256;  // 196
  const int gGemm = (NN + 127) / 128;   // 391
  const int gNode = NN / 4;             // 12500

  // ---- CSR build (dst shared by both layers) ----
  hipMemsetAsync(rowptr, 0, (NN + 1) * sizeof(int), stream);
  hist_kernel<<<gEdge, 256, 0, stream>>>(dst, rowptr);
  scan1_kernel<<<nScanB, 256, 0, stream>>>(rowptr, partial);
  scan2_kernel<<<1, 256, 0, stream>>>(partial, nScanB);
  scan3_kernel<<<nScanB + 1, 256, 0, stream>>>(rowptr, partial, cursor);
  scatter_kernel<<<gEdge, 256, 0, stream>>>(src, dst, cursor, sorted_src);

  // ---- bf16 prep ----
  f2b_kernel<<<(NN * 256 / 8 + 255) / 256, 256, 0, stream>>>(x, xb, NN * 256 / 8);
  wt_prep_kernel<<<(256 * 64 + 255) / 256, 256, 0, stream>>>(embed_W, eWT, 256, 64);
  wt_prep_kernel<<<(64 * 256 + 255) / 256, 256, 0, stream>>>(W1, w1T, 64, 256);
  wt_prep_kernel<<<(256 * 256 + 255) / 256, 256, 0, stream>>>(W2, w2T, 256, 256);
  wt_prep_kernel<<<(256 * 64 + 255) / 256, 256, 0, stream>>>(p1_W, p1T, 256, 64);

  // embed: h0b = bf16(x @ embed_W + embed_b)
  gemm_mfma<256, 64, true, true><<<gGemm, 256, 0, stream>>>(xb, eWT, embed_b, h0b, NN);

  // ---- GAT layer 1 ----
  gemm_mfma<64, 256, false, false><<<gGemm, 256, 0, stream>>>(h0b, w1T, nullptr, feat, NN);
  attn_coef_kernel<<<gNode, 256, 0, stream>>>(feat, al1, ar1, el, er);
  aggr_fused_kernel<<<gNode, 256, 0, stream>>>(rowptr, sorted_src, el, er, feat, b1, houtb);

  // ---- GAT layer 2 ----
  gemm_mfma<256, 256, false, false><<<gGemm, 256, 0, stream>>>(houtb, w2T, nullptr, feat, NN);
  attn_coef_kernel<<<gNode, 256, 0, stream>>>(feat, al2, ar2, el, er);
  aggr_fused_kernel<<<gNode, 256, 0, stream>>>(rowptr, sorted_src, el, er, feat, b2, houtb);

  // ---- head ----
  gemm_mfma<256, 64, true, false><<<gGemm, 256, 0, stream>>>(houtb, p1T, p1_b, t1, NN);
  proj2_kernel<<<gNode, 256, 0, stream>>>(t1, p2_W, p2_b, (float*)d_out);
}

// Round 5
// 509.432 us; speedup vs baseline: 3.1943x; 1.0446x over previous
//
#include <hip/hip_runtime.h>
#include <hip/hip_bf16.h>

// GAT: N=50000 nodes, E=500000 edges, IN=256, HID=64, H=4 heads (H*HID=256)
#define NN 50000
#define NE 500000
#define C_HH 256  // H*HID

typedef __attribute__((ext_vector_type(8))) short s16x8;
typedef __attribute__((ext_vector_type(4))) float f32x4;
typedef __attribute__((ext_vector_type(4))) unsigned short u16x4;
typedef unsigned short ushort_t;

__device__ __forceinline__ float lrelu(float x) { return x > 0.f ? x : 0.2f * x; }

// fp32 -> bf16 (round to nearest even), raw bits
__device__ __forceinline__ ushort_t f2bf(float f) {
  unsigned u = __float_as_uint(f);
  u = (u + 0x7FFFu + ((u >> 16) & 1u)) >> 16;
  return (ushort_t)u;
}
__device__ __forceinline__ float bf2f(ushort_t u) {
  return __uint_as_float(((unsigned)u) << 16);
}

// ---------------- combined weight transpose-convert (4 matrices, one launch) ----------------
// seg0: embed_W[256][64]  -> eWT[64][256]
// seg1: W1[64][256]       -> w1T[256][64]
// seg2: W2[256][256]      -> w2T[256][256]
// seg3: p1_W[256][64]     -> p1T[64][256]
__global__ __launch_bounds__(256) void prep_kernel(const float* __restrict__ eW,
                                                   const float* __restrict__ W1,
                                                   const float* __restrict__ W2,
                                                   const float* __restrict__ p1W,
                                                   ushort_t* __restrict__ eWT,
                                                   ushort_t* __restrict__ w1T,
                                                   ushort_t* __restrict__ w2T,
                                                   ushort_t* __restrict__ p1T) {
  int idx = blockIdx.x * 256 + threadIdx.x;
  if (idx < 16384) {                       // eWT: n=idx>>8, k=idx&255
    eWT[idx] = f2bf(eW[(idx & 255) * 64 + (idx >> 8)]);
  } else if (idx < 32768) {                // w1T: K=64
    idx -= 16384;
    w1T[idx] = f2bf(W1[(idx & 63) * 256 + (idx >> 6)]);
  } else if (idx < 98304) {                // w2T: K=256
    idx -= 32768;
    w2T[idx] = f2bf(W2[(idx & 255) * 256 + (idx >> 8)]);
  } else if (idx < 114688) {               // p1T: K=256
    idx -= 98304;
    p1T[idx] = f2bf(p1W[(idx & 255) * 64 + (idx >> 8)]);
  }
}

// ---------------- MFMA GEMM with fused epilogues ----------------
// WT is [NC][K] bf16. Block: 256 thr = 4 waves, BM=128; wave w owns rows [32w,32w+32).
// mfma_f32_16x16x32_bf16; C/D layout: col=lane&15, row=(lane>>4)*4+reg (HW-verified r4).
// EPI: 0 = f32 C store; 1 = bf16 C store; 2 = bf16 C store + el/er attn coefs;
//      3 = no C store, fused p1_b bias + dot(p2w) + sigmoid -> out[row]
template <int K, int NC, bool A_F32, bool BIAS, int EPI>
__global__ __launch_bounds__(256) void gemm_mfma(const void* __restrict__ Ain,
                                                 const ushort_t* __restrict__ WT,
                                                 const float* __restrict__ Bias,
                                                 void* __restrict__ Cout, int M,
                                                 const float* __restrict__ al,
                                                 const float* __restrict__ ar,
                                                 float* __restrict__ el,
                                                 float* __restrict__ er,
                                                 const float* __restrict__ p2w,
                                                 const float* __restrict__ p2b,
                                                 float* __restrict__ out) {
  constexpr int NT = NC / 16;  // n-tiles
  constexpr int KS = K / 32;   // k-steps
  const int wid = threadIdx.x >> 6;
  const int lane = threadIdx.x & 63;
  const int row0 = blockIdx.x * 128 + wid * 32;
  const int rA = lane & 15;   // m-index (A) / n-index (B) / col (C)
  const int kg = lane >> 4;   // k-group 0..3

  f32x4 acc[2][NT] = {};
  const s16x8 zf = {0, 0, 0, 0, 0, 0, 0, 0};

  const bool v0 = (row0 + rA) < M;
  const bool v1 = (row0 + 16 + rA) < M;
  const ushort_t* Wrow = WT + rA * K;

  if (A_F32) {
    const float* Af = (const float*)Ain;
    const float* Arow0 = Af + (size_t)(row0 + rA) * K;
    const float* Arow1 = Af + (size_t)(row0 + 16 + rA) * K;
    for (int ks = 0; ks < KS; ++ks) {
      const int k0 = ks * 32 + kg * 8;
      s16x8 a0 = zf, a1 = zf;
      if (v0) {
        const f32x4 u0 = *reinterpret_cast<const f32x4*>(Arow0 + k0);
        const f32x4 u1 = *reinterpret_cast<const f32x4*>(Arow0 + k0 + 4);
        a0[0] = (short)f2bf(u0[0]); a0[1] = (short)f2bf(u0[1]);
        a0[2] = (short)f2bf(u0[2]); a0[3] = (short)f2bf(u0[3]);
        a0[4] = (short)f2bf(u1[0]); a0[5] = (short)f2bf(u1[1]);
        a0[6] = (short)f2bf(u1[2]); a0[7] = (short)f2bf(u1[3]);
      }
      if (v1) {
        const f32x4 u0 = *reinterpret_cast<const f32x4*>(Arow1 + k0);
        const f32x4 u1 = *reinterpret_cast<const f32x4*>(Arow1 + k0 + 4);
        a1[0] = (short)f2bf(u0[0]); a1[1] = (short)f2bf(u0[1]);
        a1[2] = (short)f2bf(u0[2]); a1[3] = (short)f2bf(u0[3]);
        a1[4] = (short)f2bf(u1[0]); a1[5] = (short)f2bf(u1[1]);
        a1[6] = (short)f2bf(u1[2]); a1[7] = (short)f2bf(u1[3]);
      }
#pragma unroll
      for (int nt = 0; nt < NT; ++nt) {
        const s16x8 b = *reinterpret_cast<const s16x8*>(Wrow + nt * 16 * K + k0);
        acc[0][nt] = __builtin_amdgcn_mfma_f32_16x16x32_bf16(a0, b, acc[0][nt], 0, 0, 0);
        acc[1][nt] = __builtin_amdgcn_mfma_f32_16x16x32_bf16(a1, b, acc[1][nt], 0, 0, 0);
      }
    }
  } else {
    const ushort_t* Ab = (const ushort_t*)Ain;
    const ushort_t* Arow0 = Ab + (size_t)(row0 + rA) * K;
    const ushort_t* Arow1 = Ab + (size_t)(row0 + 16 + rA) * K;
    for (int ks = 0; ks < KS; ++ks) {
      const int k0 = ks * 32 + kg * 8;
      const s16x8 a0 = v0 ? *reinterpret_cast<const s16x8*>(Arow0 + k0) : zf;
      const s16x8 a1 = v1 ? *reinterpret_cast<const s16x8*>(Arow1 + k0) : zf;
#pragma unroll
      for (int nt = 0; nt < NT; ++nt) {
        const s16x8 b = *reinterpret_cast<const s16x8*>(Wrow + nt * 16 * K + k0);
        acc[0][nt] = __builtin_amdgcn_mfma_f32_16x16x32_bf16(a0, b, acc[0][nt], 0, 0, 0);
        acc[1][nt] = __builtin_amdgcn_mfma_f32_16x16x32_bf16(a1, b, acc[1][nt], 0, 0, 0);
      }
    }
  }

  // ---- epilogue: C store (EPI 0/1/2) ----
  if (EPI <= 2) {
#pragma unroll
    for (int nt = 0; nt < NT; ++nt) {
      const int col = nt * 16 + rA;
      const float bv = BIAS ? Bias[col] : 0.f;
#pragma unroll
      for (int mt = 0; mt < 2; ++mt) {
#pragma unroll
        for (int i = 0; i < 4; ++i) {
          const int row = row0 + mt * 16 + kg * 4 + i;
          if (row < M) {
            const float v = acc[mt][nt][i] + bv;
            if (EPI == 0)
              reinterpret_cast<float*>(Cout)[(size_t)row * NC + col] = v;
            else
              reinterpret_cast<ushort_t*>(Cout)[(size_t)row * NC + col] = f2bf(v);
          }
        }
      }
    }
  }

  // ---- epilogue: fused el/er (EPI 2; NC must be 256) ----
  if (EPI == 2) {
    float alv[NT], arv[NT];
#pragma unroll
    for (int nt = 0; nt < NT; ++nt) {
      alv[nt] = al[nt * 16 + rA];
      arv[nt] = ar[nt * 16 + rA];
    }
#pragma unroll
    for (int mt = 0; mt < 2; ++mt) {
#pragma unroll
      for (int i = 0; i < 4; ++i) {
        float e0 = 0.f, e1 = 0.f, e2 = 0.f, e3 = 0.f;
        float r0 = 0.f, r1 = 0.f, r2 = 0.f, r3 = 0.f;
#pragma unroll
        for (int j = 0; j < 4; ++j) {
          e0 = fmaf(acc[mt][0 + j][i], alv[0 + j], e0);
          e1 = fmaf(acc[mt][4 + j][i], alv[4 + j], e1);
          e2 = fmaf(acc[mt][8 + j][i], alv[8 + j], e2);
          e3 = fmaf(acc[mt][12 + j][i], alv[12 + j], e3);
          r0 = fmaf(acc[mt][0 + j][i], arv[0 + j], r0);
          r1 = fmaf(acc[mt][4 + j][i], arv[4 + j], r1);
          r2 = fmaf(acc[mt][8 + j][i], arv[8 + j], r2);
          r3 = fmaf(acc[mt][12 + j][i], arv[12 + j], r3);
        }
#pragma unroll
        for (int m = 1; m < 16; m <<= 1) {
          e0 += __shfl_xor(e0, m); e1 += __shfl_xor(e1, m);
          e2 += __shfl_xor(e2, m); e3 += __shfl_xor(e3, m);
          r0 += __shfl_xor(r0, m); r1 += __shfl_xor(r1, m);
          r2 += __shfl_xor(r2, m); r3 += __shfl_xor(r3, m);
        }
        const int row = row0 + mt * 16 + kg * 4 + i;
        if (rA == 0 && row < M) {
          *reinterpret_cast<float4*>(el + row * 4) = make_float4(e0, e1, e2, e3);
          *reinterpret_cast<float4*>(er + row * 4) = make_float4(r0, r1, r2, r3);
        }
      }
    }
  }

  // ---- epilogue: fused head projection + sigmoid (EPI 3; NC must be 64) ----
  if (EPI == 3) {
    float pv[NT], bb[NT];
#pragma unroll
    for (int nt = 0; nt < NT; ++nt) {
      pv[nt] = p2w[nt * 16 + rA];
      bb[nt] = BIAS ? Bias[nt * 16 + rA] : 0.f;
    }
    const float p2bias = p2b[0];
#pragma unroll
    for (int mt = 0; mt < 2; ++mt) {
#pragma unroll
      for (int i = 0; i < 4; ++i) {
        float v = 0.f;
#pragma unroll
        for (int nt = 0; nt < NT; ++nt) v = fmaf(acc[mt][nt][i] + bb[nt], pv[nt], v);
#pragma unroll
        for (int m = 1; m < 16; m <<= 1) v += __shfl_xor(v, m);
        const int row = row0 + mt * 16 + kg * 4 + i;
        if (rA == 0 && row < M) out[row] = 1.f / (1.f + __expf(-(v + p2bias)));
      }
    }
  }
}

// ---------------- CSR build: histogram -> scan -> scatter ----------------
__global__ __launch_bounds__(256) void hist_kernel(const int* __restrict__ dst,
                                                   int* __restrict__ rowptr) {
  const int e = blockIdx.x * 256 + threadIdx.x;
  if (e < NE) atomicAdd(&rowptr[dst[e]], 1);
}

__global__ __launch_bounds__(256) void scan1_kernel(int* __restrict__ rowptr,
                                                    int* __restrict__ partial) {
  __shared__ int sh[256];
  const int t = threadIdx.x;
  const int i = blockIdx.x * 256 + t;
  const int v = (i < NN) ? rowptr[i] : 0;
  sh[t] = v;
  __syncthreads();
#pragma unroll
  for (int off = 1; off < 256; off <<= 1) {
    int x = (t >= off) ? sh[t - off] : 0;
    __syncthreads();
    sh[t] += x;
    __syncthreads();
  }
  if (i < NN) rowptr[i] = sh[t] - v;
  if (t == 255) partial[blockIdx.x] = sh[255];
}

__global__ __launch_bounds__(256) void scan2_kernel(int* __restrict__ partial, int npb) {
  __shared__ int sh[256];
  const int t = threadIdx.x;
  const int v = (t < npb) ? partial[t] : 0;
  sh[t] = v;
  __syncthreads();
#pragma unroll
  for (int off = 1; off < 256; off <<= 1) {
    int x = (t >= off) ? sh[t - off] : 0;
    __syncthreads();
    sh[t] += x;
    __syncthreads();
  }
  if (t < npb) partial[t] = sh[t] - v;
}

__global__ __launch_bounds__(256) void scan3_kernel(int* __restrict__ rowptr,
                                                    const int* __restrict__ partial,
                                                    int* __restrict__ cursor) {
  const int i = blockIdx.x * 256 + threadIdx.x;
  if (i < NN) {
    const int r = rowptr[i] + partial[i >> 8];
    rowptr[i] = r;
    cursor[i] = r;
  } else if (i == NN) {
    rowptr[NN] = NE;
  }
}

__global__ __launch_bounds__(256) void scatter_kernel(const int* __restrict__ src,
                                                      const int* __restrict__ dst,
                                                      int* __restrict__ cursor,
                                                      int* __restrict__ sorted_src) {
  const int e = blockIdx.x * 256 + threadIdx.x;
  if (e >= NE) return;
  const int pos = atomicAdd(&cursor[dst[e]], 1);
  sorted_src[pos] = src[e];
}

// ---------------- fused per-dst softmax-aggregation + bias + relu (bf16 feat) ----------------
// one 64-lane wave per dst node; lane owns cols 4l..4l+3 (all in head l>>4) -> ONE exp/edge/lane
__global__ __launch_bounds__(256) void aggr_fused_kernel(const int* __restrict__ rowptr,
                                                         const int* __restrict__ sorted_src,
                                                         const float* __restrict__ el,
                                                         const float* __restrict__ er,
                                                         const ushort_t* __restrict__ featb,
                                                         const float* __restrict__ bias,
                                                         ushort_t* __restrict__ out) {
  const int node = blockIdx.x * 4 + (threadIdx.x >> 6);
  const int lane = threadIdx.x & 63;
  const int head = lane >> 4;
  const int start = rowptr[node];
  const int end = rowptr[node + 1];
  const float4 erd = *reinterpret_cast<const float4*>(er + node * 4);
  const float erh = (head & 1) ? ((head & 2) ? erd.w : erd.y)
                               : ((head & 2) ? erd.z : erd.x);

  float a0 = 0.f, a1 = 0.f, a2 = 0.f, a3 = 0.f, s = 0.f;
  for (int e = start; e < end; ++e) {
    const int sn = sorted_src[e];
    const float4 a4 = *reinterpret_cast<const float4*>(el + sn * 4);  // broadcast
    const float elh = (head & 1) ? ((head & 2) ? a4.w : a4.y)
                                 : ((head & 2) ? a4.z : a4.x);
    const float w = __expf(lrelu(elh + erh));
    const u16x4 f4 = *reinterpret_cast<const u16x4*>(featb + (size_t)sn * C_HH + lane * 4);
    a0 = fmaf(w, bf2f(f4[0]), a0);
    a1 = fmaf(w, bf2f(f4[1]), a1);
    a2 = fmaf(w, bf2f(f4[2]), a2);
    a3 = fmaf(w, bf2f(f4[3]), a3);
    s += w;
  }
  float r0 = 0.f, r1 = 0.f, r2 = 0.f, r3 = 0.f;
  if (end > start) {
    const float inv = 1.f / s;
    r0 = a0 * inv; r1 = a1 * inv; r2 = a2 * inv; r3 = a3 * inv;
  }
  const float4 bb = *reinterpret_cast<const float4*>(bias + lane * 4);
  u16x4 o;
  o[0] = f2bf(fmaxf(r0 + bb.x, 0.f));
  o[1] = f2bf(fmaxf(r1 + bb.y, 0.f));
  o[2] = f2bf(fmaxf(r2 + bb.z, 0.f));
  o[3] = f2bf(fmaxf(r3 + bb.w, 0.f));
  *reinterpret_cast<u16x4*>(out + (size_t)node * C_HH + lane * 4) = o;
}

extern "C" void kernel_launch(void* const* d_in, const int* in_sizes, int n_in,
                              void* d_out, int out_size, void* d_ws, size_t ws_size,
                              hipStream_t stream) {
  const float* x = (const float*)d_in[0];
  const int* src = (const int*)d_in[1];
  const int* dst = (const int*)d_in[2];
  const float* embed_W = (const float*)d_in[3];
  const float* embed_b = (const float*)d_in[4];
  const float* W1 = (const float*)d_in[5];
  const float* al1 = (const float*)d_in[6];
  const float* ar1 = (const float*)d_in[7];
  const float* b1 = (const float*)d_in[8];
  const float* W2 = (const float*)d_in[9];
  const float* al2 = (const float*)d_in[10];
  const float* ar2 = (const float*)d_in[11];
  const float* b2 = (const float*)d_in[12];
  const float* p1_W = (const float*)d_in[13];
  const float* p1_b = (const float*)d_in[14];
  const float* p2_W = (const float*)d_in[15];
  const float* p2_b = (const float*)d_in[16];

  char* ws = (char*)d_ws;
  ushort_t* featb = (ushort_t*)(ws + 0);          // N*256 bf16 = 25.6 MB
  ushort_t* houtb = (ushort_t*)(ws + 25600000);   // N*256 bf16 = 25.6 MB
  ushort_t* h0b = (ushort_t*)(ws + 51200000);     // N*64 bf16 = 6.4 MB
  float* el = (float*)(ws + 57600000);            // N*4 f32
  float* er = (float*)(ws + 58400000);            // N*4 f32
  int* rowptr = (int*)(ws + 59200000);            // N+1
  int* cursor = (int*)(ws + 59500000);            // N
  int* partial = (int*)(ws + 59800000);           // 256
  int* sorted_src = (int*)(ws + 59900000);        // E = 2 MB
  ushort_t* eWT = (ushort_t*)(ws + 62000000);     // 64*256
  ushort_t* w1T = (ushort_t*)(ws + 62100000);     // 256*64
  ushort_t* w2T = (ushort_t*)(ws + 62200000);     // 256*256 = 128 KB
  ushort_t* p1T = (ushort_t*)(ws + 62400000);     // 64*256

  const int gEdge = (NE + 255) / 256;   // 1954
  const int nScanB = (NN + 255) / 256;  // 196
  const int gGemm = (NN + 127) / 128;   // 391
  const int gNode = NN / 4;             // 12500

  // ---- CSR build (dst shared by both layers) ----
  hipMemsetAsync(rowptr, 0, (NN + 1) * sizeof(int), stream);
  hist_kernel<<<gEdge, 256, 0, stream>>>(dst, rowptr);
  scan1_kernel<<<nScanB, 256, 0, stream>>>(rowptr, partial);
  scan2_kernel<<<1, 256, 0, stream>>>(partial, nScanB);
  scan3_kernel<<<nScanB + 1, 256, 0, stream>>>(rowptr, partial, cursor);
  scatter_kernel<<<gEdge, 256, 0, stream>>>(src, dst, cursor, sorted_src);

  // ---- weight prep (single launch) ----
  prep_kernel<<<448, 256, 0, stream>>>(embed_W, W1, W2, p1_W, eWT, w1T, w2T, p1T);

  // embed: h0b = bf16(x @ embed_W + embed_b)   [A fp32, converted in-register]
  gemm_mfma<256, 64, true, true, 1><<<gGemm, 256, 0, stream>>>(
      x, eWT, embed_b, h0b, NN, nullptr, nullptr, nullptr, nullptr, nullptr, nullptr, nullptr);

  // ---- GAT layer 1: featb = bf16(h0b @ W1), el/er fused ----
  gemm_mfma<64, 256, false, false, 2><<<gGemm, 256, 0, stream>>>(
      h0b, w1T, nullptr, featb, NN, al1, ar1, el, er, nullptr, nullptr, nullptr);
  aggr_fused_kernel<<<gNode, 256, 0, stream>>>(rowptr, sorted_src, el, er, featb, b1, houtb);

  // ---- GAT layer 2 ----
  gemm_mfma<256, 256, false, false, 2><<<gGemm, 256, 0, stream>>>(
      houtb, w2T, nullptr, featb, NN, al2, ar2, el, er, nullptr, nullptr, nullptr);
  aggr_fused_kernel<<<gNode, 256, 0, stream>>>(rowptr, sorted_src, el, er, featb, b2, houtb);

  // ---- head: out = sigmoid((hout @ p1_W + p1_b) @ p2_W + p2_b), fully fused ----
  gemm_mfma<256, 64, false, true, 3><<<gGemm, 256, 0, stream>>>(
      houtb, p1T, p1_b, nullptr, NN, nullptr, nullptr, nullptr, nullptr, p2_W, p2_b, (float*)d_out);
}

// Round 6
// 406.470 us; speedup vs baseline: 4.0035x; 1.2533x over previous
//
#include <hip/hip_runtime.h>
#include <hip/hip_bf16.h>

// GAT: N=50000 nodes, E=500000 edges, IN=256, HID=64, H=4 heads (H*HID=256)
#define NN 50000
#define NE 500000
#define C_HH 256  // H*HID

typedef __attribute__((ext_vector_type(8))) short s16x8;
typedef __attribute__((ext_vector_type(4))) float f32x4;
typedef __attribute__((ext_vector_type(4))) unsigned short u16x4;
typedef unsigned short ushort_t;

__device__ __forceinline__ float lrelu(float x) { return x > 0.f ? x : 0.2f * x; }

// fp32 -> bf16 (round to nearest even), raw bits
__device__ __forceinline__ ushort_t f2bf(float f) {
  unsigned u = __float_as_uint(f);
  u = (u + 0x7FFFu + ((u >> 16) & 1u)) >> 16;
  return (ushort_t)u;
}
__device__ __forceinline__ float bf2f(ushort_t u) {
  return __uint_as_float(((unsigned)u) << 16);
}
// select component `head` (0..3) of a float4 with 2 cndmasks
__device__ __forceinline__ float sel_head(float4 v, int head) {
  const float x0 = (head & 1) ? v.y : v.x;
  const float x1 = (head & 1) ? v.w : v.z;
  return (head & 2) ? x1 : x0;
}

// ---------------- combined weight transpose-convert (4 matrices, one launch) ----------------
__global__ __launch_bounds__(256) void prep_kernel(const float* __restrict__ eW,
                                                   const float* __restrict__ W1,
                                                   const float* __restrict__ W2,
                                                   const float* __restrict__ p1W,
                                                   ushort_t* __restrict__ eWT,
                                                   ushort_t* __restrict__ w1T,
                                                   ushort_t* __restrict__ w2T,
                                                   ushort_t* __restrict__ p1T) {
  int idx = blockIdx.x * 256 + threadIdx.x;
  if (idx < 16384) {                       // eWT: n=idx>>8, k=idx&255
    eWT[idx] = f2bf(eW[(idx & 255) * 64 + (idx >> 8)]);
  } else if (idx < 32768) {                // w1T: K=64
    idx -= 16384;
    w1T[idx] = f2bf(W1[(idx & 63) * 256 + (idx >> 6)]);
  } else if (idx < 98304) {                // w2T: K=256
    idx -= 32768;
    w2T[idx] = f2bf(W2[(idx & 255) * 256 + (idx >> 8)]);
  } else if (idx < 114688) {               // p1T: K=256
    idx -= 98304;
    p1T[idx] = f2bf(p1W[(idx & 255) * 64 + (idx >> 8)]);
  }
}

// ---------------- MFMA GEMM with fused epilogues ----------------
// WT is [NC][K] bf16. Block: 256 thr = 4 waves, BM=128; wave w owns rows [32w,32w+32).
// mfma_f32_16x16x32_bf16; C/D layout: col=lane&15, row=(lane>>4)*4+reg (HW-verified r4).
// EPI: 0 = f32 C store; 1 = bf16 C store; 2 = bf16 C store + el/er attn coefs;
//      3 = no C store, fused p1_b bias + dot(p2w) + sigmoid -> out[row]
template <int K, int NC, bool A_F32, bool BIAS, int EPI>
__global__ __launch_bounds__(256) void gemm_mfma(const void* __restrict__ Ain,
                                                 const ushort_t* __restrict__ WT,
                                                 const float* __restrict__ Bias,
                                                 void* __restrict__ Cout, int M,
                                                 const float* __restrict__ al,
                                                 const float* __restrict__ ar,
                                                 float* __restrict__ el,
                                                 float* __restrict__ er,
                                                 const float* __restrict__ p2w,
                                                 const float* __restrict__ p2b,
                                                 float* __restrict__ out) {
  constexpr int NT = NC / 16;  // n-tiles
  constexpr int KS = K / 32;   // k-steps
  const int wid = threadIdx.x >> 6;
  const int lane = threadIdx.x & 63;
  const int row0 = blockIdx.x * 128 + wid * 32;
  const int rA = lane & 15;   // m-index (A) / n-index (B) / col (C)
  const int kg = lane >> 4;   // k-group 0..3

  f32x4 acc[2][NT] = {};
  const s16x8 zf = {0, 0, 0, 0, 0, 0, 0, 0};

  const bool v0 = (row0 + rA) < M;
  const bool v1 = (row0 + 16 + rA) < M;
  const ushort_t* Wrow = WT + rA * K;

  if (A_F32) {
    const float* Af = (const float*)Ain;
    const float* Arow0 = Af + (size_t)(row0 + rA) * K;
    const float* Arow1 = Af + (size_t)(row0 + 16 + rA) * K;
    for (int ks = 0; ks < KS; ++ks) {
      const int k0 = ks * 32 + kg * 8;
      s16x8 a0 = zf, a1 = zf;
      if (v0) {
        const f32x4 u0 = *reinterpret_cast<const f32x4*>(Arow0 + k0);
        const f32x4 u1 = *reinterpret_cast<const f32x4*>(Arow0 + k0 + 4);
        a0[0] = (short)f2bf(u0[0]); a0[1] = (short)f2bf(u0[1]);
        a0[2] = (short)f2bf(u0[2]); a0[3] = (short)f2bf(u0[3]);
        a0[4] = (short)f2bf(u1[0]); a0[5] = (short)f2bf(u1[1]);
        a0[6] = (short)f2bf(u1[2]); a0[7] = (short)f2bf(u1[3]);
      }
      if (v1) {
        const f32x4 u0 = *reinterpret_cast<const f32x4*>(Arow1 + k0);
        const f32x4 u1 = *reinterpret_cast<const f32x4*>(Arow1 + k0 + 4);
        a1[0] = (short)f2bf(u0[0]); a1[1] = (short)f2bf(u0[1]);
        a1[2] = (short)f2bf(u0[2]); a1[3] = (short)f2bf(u0[3]);
        a1[4] = (short)f2bf(u1[0]); a1[5] = (short)f2bf(u1[1]);
        a1[6] = (short)f2bf(u1[2]); a1[7] = (short)f2bf(u1[3]);
      }
#pragma unroll
      for (int nt = 0; nt < NT; ++nt) {
        const s16x8 b = *reinterpret_cast<const s16x8*>(Wrow + nt * 16 * K + k0);
        acc[0][nt] = __builtin_amdgcn_mfma_f32_16x16x32_bf16(a0, b, acc[0][nt], 0, 0, 0);
        acc[1][nt] = __builtin_amdgcn_mfma_f32_16x16x32_bf16(a1, b, acc[1][nt], 0, 0, 0);
      }
    }
  } else {
    const ushort_t* Ab = (const ushort_t*)Ain;
    const ushort_t* Arow0 = Ab + (size_t)(row0 + rA) * K;
    const ushort_t* Arow1 = Ab + (size_t)(row0 + 16 + rA) * K;
    for (int ks = 0; ks < KS; ++ks) {
      const int k0 = ks * 32 + kg * 8;
      const s16x8 a0 = v0 ? *reinterpret_cast<const s16x8*>(Arow0 + k0) : zf;
      const s16x8 a1 = v1 ? *reinterpret_cast<const s16x8*>(Arow1 + k0) : zf;
#pragma unroll
      for (int nt = 0; nt < NT; ++nt) {
        const s16x8 b = *reinterpret_cast<const s16x8*>(Wrow + nt * 16 * K + k0);
        acc[0][nt] = __builtin_amdgcn_mfma_f32_16x16x32_bf16(a0, b, acc[0][nt], 0, 0, 0);
        acc[1][nt] = __builtin_amdgcn_mfma_f32_16x16x32_bf16(a1, b, acc[1][nt], 0, 0, 0);
      }
    }
  }

  // ---- epilogue: C store (EPI 0/1/2) ----
  if (EPI <= 2) {
#pragma unroll
    for (int nt = 0; nt < NT; ++nt) {
      const int col = nt * 16 + rA;
      const float bv = BIAS ? Bias[col] : 0.f;
#pragma unroll
      for (int mt = 0; mt < 2; ++mt) {
#pragma unroll
        for (int i = 0; i < 4; ++i) {
          const int row = row0 + mt * 16 + kg * 4 + i;
          if (row < M) {
            const float v = acc[mt][nt][i] + bv;
            if (EPI == 0)
              reinterpret_cast<float*>(Cout)[(size_t)row * NC + col] = v;
            else
              reinterpret_cast<ushort_t*>(Cout)[(size_t)row * NC + col] = f2bf(v);
          }
        }
      }
    }
  }

  // ---- epilogue: fused el/er (EPI 2; NC must be 256) ----
  if (EPI == 2) {
    float alv[NT], arv[NT];
#pragma unroll
    for (int nt = 0; nt < NT; ++nt) {
      alv[nt] = al[nt * 16 + rA];
      arv[nt] = ar[nt * 16 + rA];
    }
#pragma unroll
    for (int mt = 0; mt < 2; ++mt) {
#pragma unroll
      for (int i = 0; i < 4; ++i) {
        float e0 = 0.f, e1 = 0.f, e2 = 0.f, e3 = 0.f;
        float r0 = 0.f, r1 = 0.f, r2 = 0.f, r3 = 0.f;
#pragma unroll
        for (int j = 0; j < 4; ++j) {
          e0 = fmaf(acc[mt][0 + j][i], alv[0 + j], e0);
          e1 = fmaf(acc[mt][4 + j][i], alv[4 + j], e1);
          e2 = fmaf(acc[mt][8 + j][i], alv[8 + j], e2);
          e3 = fmaf(acc[mt][12 + j][i], alv[12 + j], e3);
          r0 = fmaf(acc[mt][0 + j][i], arv[0 + j], r0);
          r1 = fmaf(acc[mt][4 + j][i], arv[4 + j], r1);
          r2 = fmaf(acc[mt][8 + j][i], arv[8 + j], r2);
          r3 = fmaf(acc[mt][12 + j][i], arv[12 + j], r3);
        }
#pragma unroll
        for (int m = 1; m < 16; m <<= 1) {
          e0 += __shfl_xor(e0, m); e1 += __shfl_xor(e1, m);
          e2 += __shfl_xor(e2, m); e3 += __shfl_xor(e3, m);
          r0 += __shfl_xor(r0, m); r1 += __shfl_xor(r1, m);
          r2 += __shfl_xor(r2, m); r3 += __shfl_xor(r3, m);
        }
        const int row = row0 + mt * 16 + kg * 4 + i;
        if (rA == 0 && row < M) {
          *reinterpret_cast<float4*>(el + row * 4) = make_float4(e0, e1, e2, e3);
          *reinterpret_cast<float4*>(er + row * 4) = make_float4(r0, r1, r2, r3);
        }
      }
    }
  }

  // ---- epilogue: fused head projection + sigmoid (EPI 3; NC must be 64) ----
  if (EPI == 3) {
    float pv[NT], bb[NT];
#pragma unroll
    for (int nt = 0; nt < NT; ++nt) {
      pv[nt] = p2w[nt * 16 + rA];
      bb[nt] = BIAS ? Bias[nt * 16 + rA] : 0.f;
    }
    const float p2bias = p2b[0];
#pragma unroll
    for (int mt = 0; mt < 2; ++mt) {
#pragma unroll
      for (int i = 0; i < 4; ++i) {
        float v = 0.f;
#pragma unroll
        for (int nt = 0; nt < NT; ++nt) v = fmaf(acc[mt][nt][i] + bb[nt], pv[nt], v);
#pragma unroll
        for (int m = 1; m < 16; m <<= 1) v += __shfl_xor(v, m);
        const int row = row0 + mt * 16 + kg * 4 + i;
        if (rA == 0 && row < M) out[row] = 1.f / (1.f + __expf(-(v + p2bias)));
      }
    }
  }
}

// ---------------- CSR build: histogram -> scan -> scatter ----------------
__global__ __launch_bounds__(256) void hist_kernel(const int* __restrict__ dst,
                                                   int* __restrict__ rowptr) {
  const int e = blockIdx.x * 256 + threadIdx.x;
  if (e < NE) atomicAdd(&rowptr[dst[e]], 1);
}

__global__ __launch_bounds__(256) void scan1_kernel(int* __restrict__ rowptr,
                                                    int* __restrict__ partial) {
  __shared__ int sh[256];
  const int t = threadIdx.x;
  const int i = blockIdx.x * 256 + t;
  const int v = (i < NN) ? rowptr[i] : 0;
  sh[t] = v;
  __syncthreads();
#pragma unroll
  for (int off = 1; off < 256; off <<= 1) {
    int x = (t >= off) ? sh[t - off] : 0;
    __syncthreads();
    sh[t] += x;
    __syncthreads();
  }
  if (i < NN) rowptr[i] = sh[t] - v;
  if (t == 255) partial[blockIdx.x] = sh[255];
}

__global__ __launch_bounds__(256) void scan2_kernel(int* __restrict__ partial, int npb) {
  __shared__ int sh[256];
  const int t = threadIdx.x;
  const int v = (t < npb) ? partial[t] : 0;
  sh[t] = v;
  __syncthreads();
#pragma unroll
  for (int off = 1; off < 256; off <<= 1) {
    int x = (t >= off) ? sh[t - off] : 0;
    __syncthreads();
    sh[t] += x;
    __syncthreads();
  }
  if (t < npb) partial[t] = sh[t] - v;
}

__global__ __launch_bounds__(256) void scan3_kernel(int* __restrict__ rowptr,
                                                    const int* __restrict__ partial,
                                                    int* __restrict__ cursor) {
  const int i = blockIdx.x * 256 + threadIdx.x;
  if (i < NN) {
    const int r = rowptr[i] + partial[i >> 8];
    rowptr[i] = r;
    cursor[i] = r;
  } else if (i == NN) {
    rowptr[NN] = NE;
  }
}

__global__ __launch_bounds__(256) void scatter_kernel(const int* __restrict__ src,
                                                      const int* __restrict__ dst,
                                                      int* __restrict__ cursor,
                                                      int* __restrict__ sorted_src) {
  const int e = blockIdx.x * 256 + threadIdx.x;
  if (e >= NE) return;
  const int pos = atomicAdd(&cursor[dst[e]], 1);
  sorted_src[pos] = src[e];
}

// ---------------- fused per-dst softmax-aggregation + bias + relu (bf16 feat) ----------------
// one 64-lane wave per dst node; lane owns cols 4l..4l+3 (all in head l>>4).
// 4-edge software pipeline: issue 4 el loads + 4 feat gathers before consuming (MLP=8).
__global__ __launch_bounds__(256) void aggr_fused_kernel(const int* __restrict__ rowptr,
                                                         const int* __restrict__ sorted_src,
                                                         const float* __restrict__ el,
                                                         const float* __restrict__ er,
                                                         const ushort_t* __restrict__ featb,
                                                         const float* __restrict__ bias,
                                                         ushort_t* __restrict__ out) {
  const int node = blockIdx.x * 4 + (threadIdx.x >> 6);
  const int lane = threadIdx.x & 63;
  const int head = lane >> 4;
  const int start = rowptr[node];
  const int end = rowptr[node + 1];
  const float erh = sel_head(*reinterpret_cast<const float4*>(er + node * 4), head);
  const size_t lofs = (size_t)lane * 4;

  float a0 = 0.f, a1 = 0.f, a2 = 0.f, a3 = 0.f, s = 0.f;
  int e = start;
  const int end4 = end - 3;
  for (; e < end4; e += 4) {
    const int sn0 = sorted_src[e + 0];
    const int sn1 = sorted_src[e + 1];
    const int sn2 = sorted_src[e + 2];
    const int sn3 = sorted_src[e + 3];
    const float4 A0 = *reinterpret_cast<const float4*>(el + sn0 * 4);
    const float4 A1 = *reinterpret_cast<const float4*>(el + sn1 * 4);
    const float4 A2 = *reinterpret_cast<const float4*>(el + sn2 * 4);
    const float4 A3 = *reinterpret_cast<const float4*>(el + sn3 * 4);
    const u16x4 F0 = *reinterpret_cast<const u16x4*>(featb + (size_t)sn0 * C_HH + lofs);
    const u16x4 F1 = *reinterpret_cast<const u16x4*>(featb + (size_t)sn1 * C_HH + lofs);
    const u16x4 F2 = *reinterpret_cast<const u16x4*>(featb + (size_t)sn2 * C_HH + lofs);
    const u16x4 F3 = *reinterpret_cast<const u16x4*>(featb + (size_t)sn3 * C_HH + lofs);
    const float w0 = __expf(lrelu(sel_head(A0, head) + erh));
    const float w1 = __expf(lrelu(sel_head(A1, head) + erh));
    const float w2 = __expf(lrelu(sel_head(A2, head) + erh));
    const float w3 = __expf(lrelu(sel_head(A3, head) + erh));
    a0 = fmaf(w0, bf2f(F0[0]), a0); a1 = fmaf(w0, bf2f(F0[1]), a1);
    a2 = fmaf(w0, bf2f(F0[2]), a2); a3 = fmaf(w0, bf2f(F0[3]), a3);
    a0 = fmaf(w1, bf2f(F1[0]), a0); a1 = fmaf(w1, bf2f(F1[1]), a1);
    a2 = fmaf(w1, bf2f(F1[2]), a2); a3 = fmaf(w1, bf2f(F1[3]), a3);
    a0 = fmaf(w2, bf2f(F2[0]), a0); a1 = fmaf(w2, bf2f(F2[1]), a1);
    a2 = fmaf(w2, bf2f(F2[2]), a2); a3 = fmaf(w2, bf2f(F2[3]), a3);
    a0 = fmaf(w3, bf2f(F3[0]), a0); a1 = fmaf(w3, bf2f(F3[1]), a1);
    a2 = fmaf(w3, bf2f(F3[2]), a2); a3 = fmaf(w3, bf2f(F3[3]), a3);
    s += (w0 + w1) + (w2 + w3);
  }
  for (; e < end; ++e) {
    const int sn = sorted_src[e];
    const float4 A = *reinterpret_cast<const float4*>(el + sn * 4);
    const u16x4 F = *reinterpret_cast<const u16x4*>(featb + (size_t)sn * C_HH + lofs);
    const float w = __expf(lrelu(sel_head(A, head) + erh));
    a0 = fmaf(w, bf2f(F[0]), a0); a1 = fmaf(w, bf2f(F[1]), a1);
    a2 = fmaf(w, bf2f(F[2]), a2); a3 = fmaf(w, bf2f(F[3]), a3);
    s += w;
  }

  float r0 = 0.f, r1 = 0.f, r2 = 0.f, r3 = 0.f;
  if (end > start) {
    const float inv = 1.f / s;
    r0 = a0 * inv; r1 = a1 * inv; r2 = a2 * inv; r3 = a3 * inv;
  }
  const float4 bb = *reinterpret_cast<const float4*>(bias + lane * 4);
  u16x4 o;
  o[0] = f2bf(fmaxf(r0 + bb.x, 0.f));
  o[1] = f2bf(fmaxf(r1 + bb.y, 0.f));
  o[2] = f2bf(fmaxf(r2 + bb.z, 0.f));
  o[3] = f2bf(fmaxf(r3 + bb.w, 0.f));
  *reinterpret_cast<u16x4*>(out + (size_t)node * C_HH + lane * 4) = o;
}

extern "C" void kernel_launch(void* const* d_in, const int* in_sizes, int n_in,
                              void* d_out, int out_size, void* d_ws, size_t ws_size,
                              hipStream_t stream) {
  const float* x = (const float*)d_in[0];
  const int* src = (const int*)d_in[1];
  const int* dst = (const int*)d_in[2];
  const float* embed_W = (const float*)d_in[3];
  const float* embed_b = (const float*)d_in[4];
  const float* W1 = (const float*)d_in[5];
  const float* al1 = (const float*)d_in[6];
  const float* ar1 = (const float*)d_in[7];
  const float* b1 = (const float*)d_in[8];
  const float* W2 = (const float*)d_in[9];
  const float* al2 = (const float*)d_in[10];
  const float* ar2 = (const float*)d_in[11];
  const float* b2 = (const float*)d_in[12];
  const float* p1_W = (const float*)d_in[13];
  const float* p1_b = (const float*)d_in[14];
  const float* p2_W = (const float*)d_in[15];
  const float* p2_b = (const float*)d_in[16];

  char* ws = (char*)d_ws;
  ushort_t* featb = (ushort_t*)(ws + 0);          // N*256 bf16 = 25.6 MB
  ushort_t* houtb = (ushort_t*)(ws + 25600000);   // N*256 bf16 = 25.6 MB
  ushort_t* h0b = (ushort_t*)(ws + 51200000);     // N*64 bf16 = 6.4 MB
  float* el = (float*)(ws + 57600000);            // N*4 f32
  float* er = (float*)(ws + 58400000);            // N*4 f32
  int* rowptr = (int*)(ws + 59200000);            // N+1
  int* cursor = (int*)(ws + 59500000);            // N
  int* partial = (int*)(ws + 59800000);           // 256
  int* sorted_src = (int*)(ws + 59900000);        // E = 2 MB
  ushort_t* eWT = (ushort_t*)(ws + 62000000);     // 64*256
  ushort_t* w1T = (ushort_t*)(ws + 62100000);     // 256*64
  ushort_t* w2T = (ushort_t*)(ws + 62200000);     // 256*256 = 128 KB
  ushort_t* p1T = (ushort_t*)(ws + 62400000);     // 64*256

  const int gEdge = (NE + 255) / 256;   // 1954
  const int nScanB = (NN + 255) / 256;  // 196
  const int gGemm = (NN + 127) / 128;   // 391
  const int gNode = NN / 4;             // 12500

  // ---- CSR build (dst shared by both layers) ----
  hipMemsetAsync(rowptr, 0, (NN + 1) * sizeof(int), stream);
  hist_kernel<<<gEdge, 256, 0, stream>>>(dst, rowptr);
  scan1_kernel<<<nScanB, 256, 0, stream>>>(rowptr, partial);
  scan2_kernel<<<1, 256, 0, stream>>>(partial, nScanB);
  scan3_kernel<<<nScanB + 1, 256, 0, stream>>>(rowptr, partial, cursor);
  scatter_kernel<<<gEdge, 256, 0, stream>>>(src, dst, cursor, sorted_src);

  // ---- weight prep (single launch) ----
  prep_kernel<<<448, 256, 0, stream>>>(embed_W, W1, W2, p1_W, eWT, w1T, w2T, p1T);

  // embed: h0b = bf16(x @ embed_W + embed_b)   [A fp32, converted in-register]
  gemm_mfma<256, 64, true, true, 1><<<gGemm, 256, 0, stream>>>(
      x, eWT, embed_b, h0b, NN, nullptr, nullptr, nullptr, nullptr, nullptr, nullptr, nullptr);

  // ---- GAT layer 1: featb = bf16(h0b @ W1), el/er fused ----
  gemm_mfma<64, 256, false, false, 2><<<gGemm, 256, 0, stream>>>(
      h0b, w1T, nullptr, featb, NN, al1, ar1, el, er, nullptr, nullptr, nullptr);
  aggr_fused_kernel<<<gNode, 256, 0, stream>>>(rowptr, sorted_src, el, er, featb, b1, houtb);

  // ---- GAT layer 2 ----
  gemm_mfma<256, 256, false, false, 2><<<gGemm, 256, 0, stream>>>(
      houtb, w2T, nullptr, featb, NN, al2, ar2, el, er, nullptr, nullptr, nullptr);
  aggr_fused_kernel<<<gNode, 256, 0, stream>>>(rowptr, sorted_src, el, er, featb, b2, houtb);

  // ---- head: out = sigmoid((hout @ p1_W + p1_b) @ p2_W + p2_b), fully fused ----
  gemm_mfma<256, 64, false, true, 3><<<gGemm, 256, 0, stream>>>(
      houtb, p1T, p1_b, nullptr, NN, nullptr, nullptr, nullptr, nullptr, p2_W, p2_b, (float*)d_out);
}

// Round 7
// 379.177 us; speedup vs baseline: 4.2916x; 1.0720x over previous
//
#include <hip/hip_runtime.h>
#include <hip/hip_bf16.h>

// GAT: N=50000 nodes, E=500000 edges, IN=256, HID=64, H=4 heads (H*HID=256)
#define NN 50000
#define NE 500000
#define C_HH 256  // H*HID

typedef __attribute__((ext_vector_type(8))) short s16x8;
typedef __attribute__((ext_vector_type(4))) float f32x4;
typedef __attribute__((ext_vector_type(4))) unsigned short u16x4;
typedef unsigned short ushort_t;

__device__ __forceinline__ float lrelu(float x) { return x > 0.f ? x : 0.2f * x; }

__device__ __forceinline__ ushort_t f2bf(float f) {
  unsigned u = __float_as_uint(f);
  u = (u + 0x7FFFu + ((u >> 16) & 1u)) >> 16;
  return (ushort_t)u;
}
__device__ __forceinline__ float bf2f(ushort_t u) {
  return __uint_as_float(((unsigned)u) << 16);
}
__device__ __forceinline__ float sel_head(float4 v, int head) {
  const float x0 = (head & 1) ? v.y : v.x;
  const float x1 = (head & 1) ? v.w : v.z;
  return (head & 2) ? x1 : x0;
}

// ---------------- prep: fold embed into W1; fold p1/p2 into a vector ----------------
// WcT[n][k] = bf16( sum_j embed_W[k][j]*W1[j][n] )   (n,k < 256)
// w2T[n][k] = bf16( W2[k][n] )
// bc[n]     = sum_j embed_b[j]*W1[j][n]
// qv[k]     = sum_j p1_W[k][j]*p2_W[j]
// cv        = sum_j p1_b[j]*p2_W[j] + p2_b
__global__ __launch_bounds__(256) void prep_kernel(const float* __restrict__ eW,
                                                   const float* __restrict__ W1,
                                                   const float* __restrict__ eb,
                                                   const float* __restrict__ W2,
                                                   const float* __restrict__ p1W,
                                                   const float* __restrict__ p1b,
                                                   const float* __restrict__ p2W,
                                                   const float* __restrict__ p2b,
                                                   ushort_t* __restrict__ WcT,
                                                   ushort_t* __restrict__ w2T,
                                                   float* __restrict__ bc,
                                                   float* __restrict__ qv,
                                                   float* __restrict__ cv) {
  int idx = blockIdx.x * 256 + threadIdx.x;
  if (idx < 65536) {                       // WcT
    const int n = idx >> 8, k = idx & 255;
    float s = 0.f;
#pragma unroll 8
    for (int j = 0; j < 64; ++j) s = fmaf(eW[k * 64 + j], W1[j * 256 + n], s);
    WcT[idx] = f2bf(s);
  } else if (idx < 131072) {               // w2T
    idx -= 65536;
    const int n = idx >> 8, k = idx & 255;
    w2T[idx] = f2bf(W2[k * 256 + n]);
  } else if (idx < 131328) {               // bc
    const int n = idx - 131072;
    float s = 0.f;
#pragma unroll 8
    for (int j = 0; j < 64; ++j) s = fmaf(eb[j], W1[j * 256 + n], s);
    bc[n] = s;
  } else if (idx < 131584) {               // qv
    const int k = idx - 131328;
    float s = 0.f;
#pragma unroll 8
    for (int j = 0; j < 64; ++j) s = fmaf(p1W[k * 64 + j], p2W[j], s);
    qv[k] = s;
  } else if (idx == 131584) {              // cv
    float s = p2b[0];
    for (int j = 0; j < 64; ++j) s = fmaf(p1b[j], p2W[j], s);
    cv[0] = s;
  }
}

// ---------------- MFMA GEMM [M,256]@[256,256] + fused el/er ----------------
// Block = 256 thr = 4 waves, 32 rows/block; wave w owns cols [64w, 64w+64) = head w.
// WT is [256][256] bf16 (col-major-of-original). Grid = ceil(M/32) = 1563.
// C/D layout: col=lane&15, row=(lane>>4)*4+reg (HW-verified r4).
template <bool A_F32, bool BIAS>
__global__ __launch_bounds__(256) void gemm_fused(const void* __restrict__ Ain,
                                                  const ushort_t* __restrict__ WT,
                                                  const float* __restrict__ bc,
                                                  const float* __restrict__ al,
                                                  const float* __restrict__ ar,
                                                  float* __restrict__ el,
                                                  float* __restrict__ er,
                                                  ushort_t* __restrict__ Cout, int M) {
  const int wid = threadIdx.x >> 6;   // head / col-group
  const int lane = threadIdx.x & 63;
  const int row0 = blockIdx.x * 32;
  const int rA = lane & 15;
  const int kg = lane >> 4;
  const int c0 = wid * 64;

  f32x4 acc[2][4] = {};
  const s16x8 zf = {0, 0, 0, 0, 0, 0, 0, 0};
  const bool v0 = (row0 + rA) < M;
  const bool v1 = (row0 + 16 + rA) < M;
  const ushort_t* Wbase = WT + (size_t)(c0 + rA) * 256;

  for (int ks = 0; ks < 8; ++ks) {
    const int k0 = ks * 32 + kg * 8;
    s16x8 a0 = zf, a1 = zf;
    if (A_F32) {
      const float* Af = (const float*)Ain;
      if (v0) {
        const f32x4 u0 = *reinterpret_cast<const f32x4*>(Af + (size_t)(row0 + rA) * 256 + k0);
        const f32x4 u1 = *reinterpret_cast<const f32x4*>(Af + (size_t)(row0 + rA) * 256 + k0 + 4);
        a0[0] = (short)f2bf(u0[0]); a0[1] = (short)f2bf(u0[1]);
        a0[2] = (short)f2bf(u0[2]); a0[3] = (short)f2bf(u0[3]);
        a0[4] = (short)f2bf(u1[0]); a0[5] = (short)f2bf(u1[1]);
        a0[6] = (short)f2bf(u1[2]); a0[7] = (short)f2bf(u1[3]);
      }
      if (v1) {
        const f32x4 u0 = *reinterpret_cast<const f32x4*>(Af + (size_t)(row0 + 16 + rA) * 256 + k0);
        const f32x4 u1 = *reinterpret_cast<const f32x4*>(Af + (size_t)(row0 + 16 + rA) * 256 + k0 + 4);
        a1[0] = (short)f2bf(u0[0]); a1[1] = (short)f2bf(u0[1]);
        a1[2] = (short)f2bf(u0[2]); a1[3] = (short)f2bf(u0[3]);
        a1[4] = (short)f2bf(u1[0]); a1[5] = (short)f2bf(u1[1]);
        a1[6] = (short)f2bf(u1[2]); a1[7] = (short)f2bf(u1[3]);
      }
    } else {
      const ushort_t* Ab = (const ushort_t*)Ain;
      if (v0) a0 = *reinterpret_cast<const s16x8*>(Ab + (size_t)(row0 + rA) * 256 + k0);
      if (v1) a1 = *reinterpret_cast<const s16x8*>(Ab + (size_t)(row0 + 16 + rA) * 256 + k0);
    }
#pragma unroll
    for (int nt = 0; nt < 4; ++nt) {
      const s16x8 b = *reinterpret_cast<const s16x8*>(Wbase + nt * 16 * 256 + k0);
      acc[0][nt] = __builtin_amdgcn_mfma_f32_16x16x32_bf16(a0, b, acc[0][nt], 0, 0, 0);
      acc[1][nt] = __builtin_amdgcn_mfma_f32_16x16x32_bf16(a1, b, acc[1][nt], 0, 0, 0);
    }
  }

  // bias (layer-1 only: bc = embed_b @ W1, part of feat before attention)
  if (BIAS) {
#pragma unroll
    for (int nt = 0; nt < 4; ++nt) {
      const float bv = bc[c0 + nt * 16 + rA];
#pragma unroll
      for (int mt = 0; mt < 2; ++mt)
#pragma unroll
        for (int i = 0; i < 4; ++i) acc[mt][nt][i] += bv;
    }
  }

  // store bf16 C
#pragma unroll
  for (int nt = 0; nt < 4; ++nt) {
    const int col = c0 + nt * 16 + rA;
#pragma unroll
    for (int mt = 0; mt < 2; ++mt) {
#pragma unroll
      for (int i = 0; i < 4; ++i) {
        const int row = row0 + mt * 16 + kg * 4 + i;
        if (row < M) Cout[(size_t)row * 256 + col] = f2bf(acc[mt][nt][i]);
      }
    }
  }

  // fused el/er for head `wid`
  float alv[4], arv[4];
#pragma unroll
  for (int nt = 0; nt < 4; ++nt) {
    alv[nt] = al[c0 + nt * 16 + rA];
    arv[nt] = ar[c0 + nt * 16 + rA];
  }
#pragma unroll
  for (int mt = 0; mt < 2; ++mt) {
#pragma unroll
    for (int i = 0; i < 4; ++i) {
      float e = 0.f, r = 0.f;
#pragma unroll
      for (int nt = 0; nt < 4; ++nt) {
        e = fmaf(acc[mt][nt][i], alv[nt], e);
        r = fmaf(acc[mt][nt][i], arv[nt], r);
      }
#pragma unroll
      for (int m = 1; m < 16; m <<= 1) {
        e += __shfl_xor(e, m);
        r += __shfl_xor(r, m);
      }
      const int row = row0 + mt * 16 + kg * 4 + i;
      if (rA == 0 && row < M) {
        el[row * 4 + wid] = e;
        er[row * 4 + wid] = r;
      }
    }
  }
}

// ---------------- CSR build: histogram -> scan -> scatter ----------------
__global__ __launch_bounds__(256) void hist_kernel(const int* __restrict__ dst,
                                                   int* __restrict__ rowptr) {
  const int e = blockIdx.x * 256 + threadIdx.x;
  if (e < NE) atomicAdd(&rowptr[dst[e]], 1);
}

__global__ __launch_bounds__(256) void scan1_kernel(int* __restrict__ rowptr,
                                                    int* __restrict__ partial) {
  __shared__ int sh[256];
  const int t = threadIdx.x;
  const int i = blockIdx.x * 256 + t;
  const int v = (i < NN) ? rowptr[i] : 0;
  sh[t] = v;
  __syncthreads();
#pragma unroll
  for (int off = 1; off < 256; off <<= 1) {
    int x = (t >= off) ? sh[t - off] : 0;
    __syncthreads();
    sh[t] += x;
    __syncthreads();
  }
  if (i < NN) rowptr[i] = sh[t] - v;
  if (t == 255) partial[blockIdx.x] = sh[255];
}

__global__ __launch_bounds__(256) void scan2_kernel(int* __restrict__ partial, int npb) {
  __shared__ int sh[256];
  const int t = threadIdx.x;
  const int v = (t < npb) ? partial[t] : 0;
  sh[t] = v;
  __syncthreads();
#pragma unroll
  for (int off = 1; off < 256; off <<= 1) {
    int x = (t >= off) ? sh[t - off] : 0;
    __syncthreads();
    sh[t] += x;
    __syncthreads();
  }
  if (t < npb) partial[t] = sh[t] - v;
}

__global__ __launch_bounds__(256) void scan3_kernel(int* __restrict__ rowptr,
                                                    const int* __restrict__ partial,
                                                    int* __restrict__ cursor) {
  const int i = blockIdx.x * 256 + threadIdx.x;
  if (i < NN) {
    const int r = rowptr[i] + partial[i >> 8];
    rowptr[i] = r;
    cursor[i] = r;
  } else if (i == NN) {
    rowptr[NN] = NE;
  }
}

__global__ __launch_bounds__(256) void scatter_kernel(const int* __restrict__ src,
                                                      const int* __restrict__ dst,
                                                      int* __restrict__ cursor,
                                                      int* __restrict__ sorted_src) {
  const int e = blockIdx.x * 256 + threadIdx.x;
  if (e >= NE) return;
  const int pos = atomicAdd(&cursor[dst[e]], 1);
  sorted_src[pos] = src[e];
}

// ---------------- fused per-dst softmax-aggregation + bias + relu (bf16 feat) ----------------
// one 64-lane wave per dst node; lane owns cols 4l..4l+3 (all in head l>>4).
// 4-edge software pipeline (MLP=8 outstanding loads).
__global__ __launch_bounds__(256) void aggr_fused_kernel(const int* __restrict__ rowptr,
                                                         const int* __restrict__ sorted_src,
                                                         const float* __restrict__ el,
                                                         const float* __restrict__ er,
                                                         const ushort_t* __restrict__ featb,
                                                         const float* __restrict__ bias,
                                                         ushort_t* __restrict__ out) {
  const int node = blockIdx.x * 4 + (threadIdx.x >> 6);
  const int lane = threadIdx.x & 63;
  const int head = lane >> 4;
  const int start = rowptr[node];
  const int end = rowptr[node + 1];
  const float erh = sel_head(*reinterpret_cast<const float4*>(er + node * 4), head);
  const size_t lofs = (size_t)lane * 4;

  float a0 = 0.f, a1 = 0.f, a2 = 0.f, a3 = 0.f, s = 0.f;
  int e = start;
  const int end4 = end - 3;
  for (; e < end4; e += 4) {
    const int sn0 = sorted_src[e + 0];
    const int sn1 = sorted_src[e + 1];
    const int sn2 = sorted_src[e + 2];
    const int sn3 = sorted_src[e + 3];
    const float4 A0 = *reinterpret_cast<const float4*>(el + sn0 * 4);
    const float4 A1 = *reinterpret_cast<const float4*>(el + sn1 * 4);
    const float4 A2 = *reinterpret_cast<const float4*>(el + sn2 * 4);
    const float4 A3 = *reinterpret_cast<const float4*>(el + sn3 * 4);
    const u16x4 F0 = *reinterpret_cast<const u16x4*>(featb + (size_t)sn0 * C_HH + lofs);
    const u16x4 F1 = *reinterpret_cast<const u16x4*>(featb + (size_t)sn1 * C_HH + lofs);
    const u16x4 F2 = *reinterpret_cast<const u16x4*>(featb + (size_t)sn2 * C_HH + lofs);
    const u16x4 F3 = *reinterpret_cast<const u16x4*>(featb + (size_t)sn3 * C_HH + lofs);
    const float w0 = __expf(lrelu(sel_head(A0, head) + erh));
    const float w1 = __expf(lrelu(sel_head(A1, head) + erh));
    const float w2 = __expf(lrelu(sel_head(A2, head) + erh));
    const float w3 = __expf(lrelu(sel_head(A3, head) + erh));
    a0 = fmaf(w0, bf2f(F0[0]), a0); a1 = fmaf(w0, bf2f(F0[1]), a1);
    a2 = fmaf(w0, bf2f(F0[2]), a2); a3 = fmaf(w0, bf2f(F0[3]), a3);
    a0 = fmaf(w1, bf2f(F1[0]), a0); a1 = fmaf(w1, bf2f(F1[1]), a1);
    a2 = fmaf(w1, bf2f(F1[2]), a2); a3 = fmaf(w1, bf2f(F1[3]), a3);
    a0 = fmaf(w2, bf2f(F2[0]), a0); a1 = fmaf(w2, bf2f(F2[1]), a1);
    a2 = fmaf(w2, bf2f(F2[2]), a2); a3 = fmaf(w2, bf2f(F2[3]), a3);
    a0 = fmaf(w3, bf2f(F3[0]), a0); a1 = fmaf(w3, bf2f(F3[1]), a1);
    a2 = fmaf(w3, bf2f(F3[2]), a2); a3 = fmaf(w3, bf2f(F3[3]), a3);
    s += (w0 + w1) + (w2 + w3);
  }
  for (; e < end; ++e) {
    const int sn = sorted_src[e];
    const float4 A = *reinterpret_cast<const float4*>(el + sn * 4);
    const u16x4 F = *reinterpret_cast<const u16x4*>(featb + (size_t)sn * C_HH + lofs);
    const float w = __expf(lrelu(sel_head(A, head) + erh));
    a0 = fmaf(w, bf2f(F[0]), a0); a1 = fmaf(w, bf2f(F[1]), a1);
    a2 = fmaf(w, bf2f(F[2]), a2); a3 = fmaf(w, bf2f(F[3]), a3);
    s += w;
  }

  float r0 = 0.f, r1 = 0.f, r2 = 0.f, r3 = 0.f;
  if (end > start) {
    const float inv = 1.f / s;
    r0 = a0 * inv; r1 = a1 * inv; r2 = a2 * inv; r3 = a3 * inv;
  }
  const float4 bb = *reinterpret_cast<const float4*>(bias + lane * 4);
  u16x4 o;
  o[0] = f2bf(fmaxf(r0 + bb.x, 0.f));
  o[1] = f2bf(fmaxf(r1 + bb.y, 0.f));
  o[2] = f2bf(fmaxf(r2 + bb.z, 0.f));
  o[3] = f2bf(fmaxf(r3 + bb.w, 0.f));
  *reinterpret_cast<u16x4*>(out + (size_t)node * C_HH + lane * 4) = o;
}

// ---------------- head: out[n] = sigmoid(hout[n]·qv + cv), wave per node ----------------
__global__ __launch_bounds__(256) void head_kernel(const ushort_t* __restrict__ houtb,
                                                   const float* __restrict__ qv,
                                                   const float* __restrict__ cv,
                                                   float* __restrict__ out) {
  const int node = blockIdx.x * 4 + (threadIdx.x >> 6);
  const int lane = threadIdx.x & 63;
  const u16x4 f = *reinterpret_cast<const u16x4*>(houtb + (size_t)node * C_HH + lane * 4);
  const float4 q = *reinterpret_cast<const float4*>(qv + lane * 4);
  float v = bf2f(f[0]) * q.x + bf2f(f[1]) * q.y + bf2f(f[2]) * q.z + bf2f(f[3]) * q.w;
#pragma unroll
  for (int off = 32; off; off >>= 1) v += __shfl_xor(v, off);
  if (lane == 0) out[node] = 1.f / (1.f + __expf(-(v + cv[0])));
}

extern "C" void kernel_launch(void* const* d_in, const int* in_sizes, int n_in,
                              void* d_out, int out_size, void* d_ws, size_t ws_size,
                              hipStream_t stream) {
  const float* x = (const float*)d_in[0];
  const int* src = (const int*)d_in[1];
  const int* dst = (const int*)d_in[2];
  const float* embed_W = (const float*)d_in[3];
  const float* embed_b = (const float*)d_in[4];
  const float* W1 = (const float*)d_in[5];
  const float* al1 = (const float*)d_in[6];
  const float* ar1 = (const float*)d_in[7];
  const float* b1 = (const float*)d_in[8];
  const float* W2 = (const float*)d_in[9];
  const float* al2 = (const float*)d_in[10];
  const float* ar2 = (const float*)d_in[11];
  const float* b2 = (const float*)d_in[12];
  const float* p1_W = (const float*)d_in[13];
  const float* p1_b = (const float*)d_in[14];
  const float* p2_W = (const float*)d_in[15];
  const float* p2_b = (const float*)d_in[16];

  char* ws = (char*)d_ws;
  ushort_t* featb = (ushort_t*)(ws + 0);          // N*256 bf16 = 25.6 MB
  ushort_t* houtb = (ushort_t*)(ws + 25600000);   // N*256 bf16 = 25.6 MB
  float* el = (float*)(ws + 51200000);            // N*4 f32
  float* er = (float*)(ws + 52000000);            // N*4 f32
  int* rowptr = (int*)(ws + 52800000);            // N+1
  int* cursor = (int*)(ws + 53100000);            // N
  int* partial = (int*)(ws + 53400000);           // 256
  int* sorted_src = (int*)(ws + 53500000);        // E = 2 MB
  ushort_t* WcT = (ushort_t*)(ws + 55600000);     // 256*256 bf16 = 128 KB
  ushort_t* w2T = (ushort_t*)(ws + 55800000);     // 256*256 bf16 = 128 KB
  float* bc = (float*)(ws + 56000000);            // 256 f32
  float* qv = (float*)(ws + 56010000);            // 256 f32
  float* cv = (float*)(ws + 56020000);            // 1 f32

  const int gEdge = (NE + 255) / 256;   // 1954
  const int nScanB = (NN + 255) / 256;  // 196
  const int gGemm = (NN + 31) / 32;     // 1563
  const int gNode = NN / 4;             // 12500

  // ---- CSR build (dst shared by both layers) ----
  hipMemsetAsync(rowptr, 0, (NN + 1) * sizeof(int), stream);
  hist_kernel<<<gEdge, 256, 0, stream>>>(dst, rowptr);
  scan1_kernel<<<nScanB, 256, 0, stream>>>(rowptr, partial);
  scan2_kernel<<<1, 256, 0, stream>>>(partial, nScanB);
  scan3_kernel<<<nScanB + 1, 256, 0, stream>>>(rowptr, partial, cursor);
  scatter_kernel<<<gEdge, 256, 0, stream>>>(src, dst, cursor, sorted_src);

  // ---- weight prep: Wc = eW@W1, bc = eb@W1, q = p1@p2, c ----
  prep_kernel<<<515, 256, 0, stream>>>(embed_W, W1, embed_b, W2, p1_W, p1_b, p2_W, p2_b,
                                       WcT, w2T, bc, qv, cv);

  // ---- GAT layer 1: featb = bf16(x @ Wc + bc), el/er fused ----
  gemm_fused<true, true><<<gGemm, 256, 0, stream>>>(x, WcT, bc, al1, ar1, el, er, featb, NN);
  aggr_fused_kernel<<<gNode, 256, 0, stream>>>(rowptr, sorted_src, el, er, featb, b1, houtb);

  // ---- GAT layer 2: featb = bf16(houtb @ W2), el/er fused ----
  gemm_fused<false, false><<<gGemm, 256, 0, stream>>>(houtb, w2T, nullptr, al2, ar2, el, er, featb, NN);
  aggr_fused_kernel<<<gNode, 256, 0, stream>>>(rowptr, sorted_src, el, er, featb, b2, houtb);

  // ---- head: out = sigmoid(houtb·qv + cv) ----
  head_kernel<<<gNode, 256, 0, stream>>>(houtb, qv, cv, (float*)d_out);
}

// Round 8
// 371.239 us; speedup vs baseline: 4.3834x; 1.0214x over previous
//
#include <hip/hip_runtime.h>
#include <hip/hip_bf16.h>

// GAT: N=50000 nodes, E=500000 edges, IN=256, HID=64, H=4 heads (H*HID=256)
#define NN 50000
#define NE 500000
#define C_HH 256  // H*HID

typedef __attribute__((ext_vector_type(8))) short s16x8;
typedef __attribute__((ext_vector_type(4))) float f32x4;
typedef __attribute__((ext_vector_type(4))) unsigned short u16x4;
typedef unsigned short ushort_t;

__device__ __forceinline__ float lrelu(float x) { return x > 0.f ? x : 0.2f * x; }

__device__ __forceinline__ ushort_t f2bf(float f) {
  unsigned u = __float_as_uint(f);
  u = (u + 0x7FFFu + ((u >> 16) & 1u)) >> 16;
  return (ushort_t)u;
}
__device__ __forceinline__ float bf2f(ushort_t u) {
  return __uint_as_float(((unsigned)u) << 16);
}
__device__ __forceinline__ float sel_head(float4 v, int head) {
  const float x0 = (head & 1) ? v.y : v.x;
  const float x1 = (head & 1) ? v.w : v.z;
  return (head & 2) ? x1 : x0;
}

// ---------------- x -> bf16 bulk convert (grid-stride, 8 elems/thread) ----------------
__global__ __launch_bounds__(256) void xb_kernel(const float* __restrict__ in,
                                                 ushort_t* __restrict__ out) {
  const int n8 = NN * 256 / 8;
  for (int i = blockIdx.x * 256 + threadIdx.x; i < n8; i += gridDim.x * 256) {
    const f32x4 v0 = reinterpret_cast<const f32x4*>(in)[2 * i];
    const f32x4 v1 = reinterpret_cast<const f32x4*>(in)[2 * i + 1];
    s16x8 o;
    o[0] = (short)f2bf(v0[0]); o[1] = (short)f2bf(v0[1]);
    o[2] = (short)f2bf(v0[2]); o[3] = (short)f2bf(v0[3]);
    o[4] = (short)f2bf(v1[0]); o[5] = (short)f2bf(v1[1]);
    o[6] = (short)f2bf(v1[2]); o[7] = (short)f2bf(v1[3]);
    reinterpret_cast<s16x8*>(out)[i] = o;
  }
}

// ---------------- prep: fold embed into W1; fold p1/p2 into a vector ----------------
__global__ __launch_bounds__(256) void prep_kernel(const float* __restrict__ eW,
                                                   const float* __restrict__ W1,
                                                   const float* __restrict__ eb,
                                                   const float* __restrict__ W2,
                                                   const float* __restrict__ p1W,
                                                   const float* __restrict__ p1b,
                                                   const float* __restrict__ p2W,
                                                   const float* __restrict__ p2b,
                                                   ushort_t* __restrict__ WcT,
                                                   ushort_t* __restrict__ w2T,
                                                   float* __restrict__ bc,
                                                   float* __restrict__ qv,
                                                   float* __restrict__ cv) {
  int idx = blockIdx.x * 256 + threadIdx.x;
  if (idx < 65536) {                       // WcT[n][k] = bf16(sum_j eW[k][j]*W1[j][n])
    const int n = idx >> 8, k = idx & 255;
    float s = 0.f;
#pragma unroll 8
    for (int j = 0; j < 64; ++j) s = fmaf(eW[k * 64 + j], W1[j * 256 + n], s);
    WcT[idx] = f2bf(s);
  } else if (idx < 131072) {               // w2T[n][k] = bf16(W2[k][n])
    idx -= 65536;
    const int n = idx >> 8, k = idx & 255;
    w2T[idx] = f2bf(W2[k * 256 + n]);
  } else if (idx < 131328) {               // bc
    const int n = idx - 131072;
    float s = 0.f;
#pragma unroll 8
    for (int j = 0; j < 64; ++j) s = fmaf(eb[j], W1[j * 256 + n], s);
    bc[n] = s;
  } else if (idx < 131584) {               // qv
    const int k = idx - 131328;
    float s = 0.f;
#pragma unroll 8
    for (int j = 0; j < 64; ++j) s = fmaf(p1W[k * 64 + j], p2W[j], s);
    qv[k] = s;
  } else if (idx == 131584) {              // cv
    float s = p2b[0];
    for (int j = 0; j < 64; ++j) s = fmaf(p1b[j], p2W[j], s);
    cv[0] = s;
  }
}

// ---------------- MFMA GEMM [M,256]@[256,256] + fused el/er, deep-MLP form ----------------
// Block = 256 thr = 4 waves, 32 rows/block; wave w owns cols [64w,64w+64) = head w.
// ALL 16 A-fragments + 32 B-fragments loaded into registers up-front (48 VMEM in flight),
// then 64 MFMAs. ~240 VGPR, __launch_bounds__(256,2) pins 2 waves/SIMD.
// C/D layout: col=lane&15, row=(lane>>4)*4+reg (HW-verified r4).
template <bool BIAS>
__global__ __launch_bounds__(256, 2) void gemm_fused(const ushort_t* __restrict__ A,
                                                     const ushort_t* __restrict__ WT,
                                                     const float* __restrict__ bc,
                                                     const float* __restrict__ al,
                                                     const float* __restrict__ ar,
                                                     float* __restrict__ el,
                                                     float* __restrict__ er,
                                                     ushort_t* __restrict__ Cout, int M) {
  const int wid = threadIdx.x >> 6;   // head / col-group
  const int lane = threadIdx.x & 63;
  const int row0 = blockIdx.x * 32;
  const int rA = lane & 15;
  const int kg = lane >> 4;
  const int c0 = wid * 64;

  const s16x8 zf = {0, 0, 0, 0, 0, 0, 0, 0};
  const bool v0 = (row0 + rA) < M;
  const bool v1 = (row0 + 16 + rA) < M;
  const ushort_t* Arow0 = A + (size_t)(row0 + rA) * 256;
  const ushort_t* Arow1 = A + (size_t)(row0 + 16 + rA) * 256;
  const ushort_t* Wbase = WT + (size_t)(c0 + rA) * 256;

  // ---- phase 1: issue ALL loads (A first: HBM long-pole; then B: L2-resident) ----
  s16x8 a0[8], a1[8];
#pragma unroll
  for (int ks = 0; ks < 8; ++ks) {
    const int k0 = ks * 32 + kg * 8;
    a0[ks] = v0 ? *reinterpret_cast<const s16x8*>(Arow0 + k0) : zf;
    a1[ks] = v1 ? *reinterpret_cast<const s16x8*>(Arow1 + k0) : zf;
  }
  s16x8 b[8][4];
#pragma unroll
  for (int ks = 0; ks < 8; ++ks) {
    const int k0 = ks * 32 + kg * 8;
#pragma unroll
    for (int nt = 0; nt < 4; ++nt)
      b[ks][nt] = *reinterpret_cast<const s16x8*>(Wbase + nt * 16 * 256 + k0);
  }

  // ---- phase 2: 64 MFMAs ----
  f32x4 acc[2][4] = {};
#pragma unroll
  for (int ks = 0; ks < 8; ++ks) {
#pragma unroll
    for (int nt = 0; nt < 4; ++nt) {
      acc[0][nt] = __builtin_amdgcn_mfma_f32_16x16x32_bf16(a0[ks], b[ks][nt], acc[0][nt], 0, 0, 0);
      acc[1][nt] = __builtin_amdgcn_mfma_f32_16x16x32_bf16(a1[ks], b[ks][nt], acc[1][nt], 0, 0, 0);
    }
  }

  if (BIAS) {
#pragma unroll
    for (int nt = 0; nt < 4; ++nt) {
      const float bv = bc[c0 + nt * 16 + rA];
#pragma unroll
      for (int mt = 0; mt < 2; ++mt)
#pragma unroll
        for (int i = 0; i < 4; ++i) acc[mt][nt][i] += bv;
    }
  }

  // store bf16 C
#pragma unroll
  for (int nt = 0; nt < 4; ++nt) {
    const int col = c0 + nt * 16 + rA;
#pragma unroll
    for (int mt = 0; mt < 2; ++mt) {
#pragma unroll
      for (int i = 0; i < 4; ++i) {
        const int row = row0 + mt * 16 + kg * 4 + i;
        if (row < M) Cout[(size_t)row * 256 + col] = f2bf(acc[mt][nt][i]);
      }
    }
  }

  // fused el/er for head `wid`
  float alv[4], arv[4];
#pragma unroll
  for (int nt = 0; nt < 4; ++nt) {
    alv[nt] = al[c0 + nt * 16 + rA];
    arv[nt] = ar[c0 + nt * 16 + rA];
  }
#pragma unroll
  for (int mt = 0; mt < 2; ++mt) {
#pragma unroll
    for (int i = 0; i < 4; ++i) {
      float e = 0.f, r = 0.f;
#pragma unroll
      for (int nt = 0; nt < 4; ++nt) {
        e = fmaf(acc[mt][nt][i], alv[nt], e);
        r = fmaf(acc[mt][nt][i], arv[nt], r);
      }
#pragma unroll
      for (int m = 1; m < 16; m <<= 1) {
        e += __shfl_xor(e, m);
        r += __shfl_xor(r, m);
      }
      const int row = row0 + mt * 16 + kg * 4 + i;
      if (rA == 0 && row < M) {
        el[row * 4 + wid] = e;
        er[row * 4 + wid] = r;
      }
    }
  }
}

// ---------------- CSR build: histogram -> scan -> scatter ----------------
__global__ __launch_bounds__(256) void hist_kernel(const int* __restrict__ dst,
                                                   int* __restrict__ rowptr) {
  const int e = blockIdx.x * 256 + threadIdx.x;
  if (e < NE) atomicAdd(&rowptr[dst[e]], 1);
}

__global__ __launch_bounds__(256) void scan1_kernel(int* __restrict__ rowptr,
                                                    int* __restrict__ partial) {
  __shared__ int sh[256];
  const int t = threadIdx.x;
  const int i = blockIdx.x * 256 + t;
  const int v = (i < NN) ? rowptr[i] : 0;
  sh[t] = v;
  __syncthreads();
#pragma unroll
  for (int off = 1; off < 256; off <<= 1) {
    int x = (t >= off) ? sh[t - off] : 0;
    __syncthreads();
    sh[t] += x;
    __syncthreads();
  }
  if (i < NN) rowptr[i] = sh[t] - v;
  if (t == 255) partial[blockIdx.x] = sh[255];
}

__global__ __launch_bounds__(256) void scan2_kernel(int* __restrict__ partial, int npb) {
  __shared__ int sh[256];
  const int t = threadIdx.x;
  const int v = (t < npb) ? partial[t] : 0;
  sh[t] = v;
  __syncthreads();
#pragma unroll
  for (int off = 1; off < 256; off <<= 1) {
    int x = (t >= off) ? sh[t - off] : 0;
    __syncthreads();
    sh[t] += x;
    __syncthreads();
  }
  if (t < npb) partial[t] = sh[t] - v;
}

__global__ __launch_bounds__(256) void scan3_kernel(int* __restrict__ rowptr,
                                                    const int* __restrict__ partial,
                                                    int* __restrict__ cursor) {
  const int i = blockIdx.x * 256 + threadIdx.x;
  if (i < NN) {
    const int r = rowptr[i] + partial[i >> 8];
    rowptr[i] = r;
    cursor[i] = r;
  } else if (i == NN) {
    rowptr[NN] = NE;
  }
}

__global__ __launch_bounds__(256) void scatter_kernel(const int* __restrict__ src,
                                                      const int* __restrict__ dst,
                                                      int* __restrict__ cursor,
                                                      int* __restrict__ sorted_src) {
  const int e = blockIdx.x * 256 + threadIdx.x;
  if (e >= NE) return;
  const int pos = atomicAdd(&cursor[dst[e]], 1);
  sorted_src[pos] = src[e];
}

// ---------------- fused per-dst softmax-aggregation + bias + relu (bf16 feat) ----------------
__global__ __launch_bounds__(256) void aggr_fused_kernel(const int* __restrict__ rowptr,
                                                         const int* __restrict__ sorted_src,
                                                         const float* __restrict__ el,
                                                         const float* __restrict__ er,
                                                         const ushort_t* __restrict__ featb,
                                                         const float* __restrict__ bias,
                                                         ushort_t* __restrict__ out) {
  const int node = blockIdx.x * 4 + (threadIdx.x >> 6);
  const int lane = threadIdx.x & 63;
  const int head = lane >> 4;
  const int start = rowptr[node];
  const int end = rowptr[node + 1];
  const float erh = sel_head(*reinterpret_cast<const float4*>(er + node * 4), head);
  const size_t lofs = (size_t)lane * 4;

  float a0 = 0.f, a1 = 0.f, a2 = 0.f, a3 = 0.f, s = 0.f;
  int e = start;
  const int end4 = end - 3;
  for (; e < end4; e += 4) {
    const int sn0 = sorted_src[e + 0];
    const int sn1 = sorted_src[e + 1];
    const int sn2 = sorted_src[e + 2];
    const int sn3 = sorted_src[e + 3];
    const float4 A0 = *reinterpret_cast<const float4*>(el + sn0 * 4);
    const float4 A1 = *reinterpret_cast<const float4*>(el + sn1 * 4);
    const float4 A2 = *reinterpret_cast<const float4*>(el + sn2 * 4);
    const float4 A3 = *reinterpret_cast<const float4*>(el + sn3 * 4);
    const u16x4 F0 = *reinterpret_cast<const u16x4*>(featb + (size_t)sn0 * C_HH + lofs);
    const u16x4 F1 = *reinterpret_cast<const u16x4*>(featb + (size_t)sn1 * C_HH + lofs);
    const u16x4 F2 = *reinterpret_cast<const u16x4*>(featb + (size_t)sn2 * C_HH + lofs);
    const u16x4 F3 = *reinterpret_cast<const u16x4*>(featb + (size_t)sn3 * C_HH + lofs);
    const float w0 = __expf(lrelu(sel_head(A0, head) + erh));
    const float w1 = __expf(lrelu(sel_head(A1, head) + erh));
    const float w2 = __expf(lrelu(sel_head(A2, head) + erh));
    const float w3 = __expf(lrelu(sel_head(A3, head) + erh));
    a0 = fmaf(w0, bf2f(F0[0]), a0); a1 = fmaf(w0, bf2f(F0[1]), a1);
    a2 = fmaf(w0, bf2f(F0[2]), a2); a3 = fmaf(w0, bf2f(F0[3]), a3);
    a0 = fmaf(w1, bf2f(F1[0]), a0); a1 = fmaf(w1, bf2f(F1[1]), a1);
    a2 = fmaf(w1, bf2f(F1[2]), a2); a3 = fmaf(w1, bf2f(F1[3]), a3);
    a0 = fmaf(w2, bf2f(F2[0]), a0); a1 = fmaf(w2, bf2f(F2[1]), a1);
    a2 = fmaf(w2, bf2f(F2[2]), a2); a3 = fmaf(w2, bf2f(F2[3]), a3);
    a0 = fmaf(w3, bf2f(F3[0]), a0); a1 = fmaf(w3, bf2f(F3[1]), a1);
    a2 = fmaf(w3, bf2f(F3[2]), a2); a3 = fmaf(w3, bf2f(F3[3]), a3);
    s += (w0 + w1) + (w2 + w3);
  }
  for (; e < end; ++e) {
    const int sn = sorted_src[e];
    const float4 A = *reinterpret_cast<const float4*>(el + sn * 4);
    const u16x4 F = *reinterpret_cast<const u16x4*>(featb + (size_t)sn * C_HH + lofs);
    const float w = __expf(lrelu(sel_head(A, head) + erh));
    a0 = fmaf(w, bf2f(F[0]), a0); a1 = fmaf(w, bf2f(F[1]), a1);
    a2 = fmaf(w, bf2f(F[2]), a2); a3 = fmaf(w, bf2f(F[3]), a3);
    s += w;
  }

  float r0 = 0.f, r1 = 0.f, r2 = 0.f, r3 = 0.f;
  if (end > start) {
    const float inv = 1.f / s;
    r0 = a0 * inv; r1 = a1 * inv; r2 = a2 * inv; r3 = a3 * inv;
  }
  const float4 bb = *reinterpret_cast<const float4*>(bias + lane * 4);
  u16x4 o;
  o[0] = f2bf(fmaxf(r0 + bb.x, 0.f));
  o[1] = f2bf(fmaxf(r1 + bb.y, 0.f));
  o[2] = f2bf(fmaxf(r2 + bb.z, 0.f));
  o[3] = f2bf(fmaxf(r3 + bb.w, 0.f));
  *reinterpret_cast<u16x4*>(out + (size_t)node * C_HH + lane * 4) = o;
}

// ---------------- head: out[n] = sigmoid(hout[n]·qv + cv), wave per node ----------------
__global__ __launch_bounds__(256) void head_kernel(const ushort_t* __restrict__ houtb,
                                                   const float* __restrict__ qv,
                                                   const float* __restrict__ cv,
                                                   float* __restrict__ out) {
  const int node = blockIdx.x * 4 + (threadIdx.x >> 6);
  const int lane = threadIdx.x & 63;
  const u16x4 f = *reinterpret_cast<const u16x4*>(houtb + (size_t)node * C_HH + lane * 4);
  const float4 q = *reinterpret_cast<const float4*>(qv + lane * 4);
  float v = bf2f(f[0]) * q.x + bf2f(f[1]) * q.y + bf2f(f[2]) * q.z + bf2f(f[3]) * q.w;
#pragma unroll
  for (int off = 32; off; off >>= 1) v += __shfl_xor(v, off);
  if (lane == 0) out[node] = 1.f / (1.f + __expf(-(v + cv[0])));
}

extern "C" void kernel_launch(void* const* d_in, const int* in_sizes, int n_in,
                              void* d_out, int out_size, void* d_ws, size_t ws_size,
                              hipStream_t stream) {
  const float* x = (const float*)d_in[0];
  const int* src = (const int*)d_in[1];
  const int* dst = (const int*)d_in[2];
  const float* embed_W = (const float*)d_in[3];
  const float* embed_b = (const float*)d_in[4];
  const float* W1 = (const float*)d_in[5];
  const float* al1 = (const float*)d_in[6];
  const float* ar1 = (const float*)d_in[7];
  const float* b1 = (const float*)d_in[8];
  const float* W2 = (const float*)d_in[9];
  const float* al2 = (const float*)d_in[10];
  const float* ar2 = (const float*)d_in[11];
  const float* b2 = (const float*)d_in[12];
  const float* p1_W = (const float*)d_in[13];
  const float* p1_b = (const float*)d_in[14];
  const float* p2_W = (const float*)d_in[15];
  const float* p2_b = (const float*)d_in[16];

  char* ws = (char*)d_ws;
  ushort_t* featb = (ushort_t*)(ws + 0);          // N*256 bf16 = 25.6 MB
  ushort_t* houtb = (ushort_t*)(ws + 25600000);   // N*256 bf16 = 25.6 MB
  ushort_t* xb = (ushort_t*)(ws + 51200000);      // N*256 bf16 = 25.6 MB
  float* el = (float*)(ws + 76800000);            // N*4 f32
  float* er = (float*)(ws + 77600000);            // N*4 f32
  int* rowptr = (int*)(ws + 78400000);            // N+1
  int* cursor = (int*)(ws + 78700000);            // N
  int* partial = (int*)(ws + 79000000);           // 256
  int* sorted_src = (int*)(ws + 79100000);        // E = 2 MB
  ushort_t* WcT = (ushort_t*)(ws + 81200000);     // 256*256 bf16 = 128 KB
  ushort_t* w2T = (ushort_t*)(ws + 81400000);     // 256*256 bf16 = 128 KB
  float* bc = (float*)(ws + 81600000);            // 256 f32
  float* qv = (float*)(ws + 81610000);            // 256 f32
  float* cv = (float*)(ws + 81620000);            // 1 f32

  const int gEdge = (NE + 255) / 256;   // 1954
  const int nScanB = (NN + 255) / 256;  // 196
  const int gGemm = (NN + 31) / 32;     // 1563
  const int gNode = NN / 4;             // 12500

  // ---- CSR build (dst shared by both layers) ----
  hipMemsetAsync(rowptr, 0, (NN + 1) * sizeof(int), stream);
  hist_kernel<<<gEdge, 256, 0, stream>>>(dst, rowptr);
  scan1_kernel<<<nScanB, 256, 0, stream>>>(rowptr, partial);
  scan2_kernel<<<1, 256, 0, stream>>>(partial, nScanB);
  scan3_kernel<<<nScanB + 1, 256, 0, stream>>>(rowptr, partial, cursor);
  scatter_kernel<<<gEdge, 256, 0, stream>>>(src, dst, cursor, sorted_src);

  // ---- weight prep + x conversion ----
  prep_kernel<<<515, 256, 0, stream>>>(embed_W, W1, embed_b, W2, p1_W, p1_b, p2_W, p2_b,
                                       WcT, w2T, bc, qv, cv);
  xb_kernel<<<2048, 256, 0, stream>>>(x, xb);

  // ---- GAT layer 1: featb = bf16(xb @ Wc + bc), el/er fused ----
  gemm_fused<true><<<gGemm, 256, 0, stream>>>(xb, WcT, bc, al1, ar1, el, er, featb, NN);
  aggr_fused_kernel<<<gNode, 256, 0, stream>>>(rowptr, sorted_src, el, er, featb, b1, houtb);

  // ---- GAT layer 2: featb = bf16(houtb @ W2), el/er fused ----
  gemm_fused<false><<<gGemm, 256, 0, stream>>>(houtb, w2T, nullptr, al2, ar2, el, er, featb, NN);
  aggr_fused_kernel<<<gNode, 256, 0, stream>>>(rowptr, sorted_src, el, er, featb, b2, houtb);

  // ---- head: out = sigmoid(houtb·qv + cv) ----
  head_kernel<<<gNode, 256, 0, stream>>>(houtb, qv, cv, (float*)d_out);
}